// Round 5
// baseline (16157.634 us; speedup 1.0000x reference)
//
#include <hip/hip_runtime.h>
#include <cmath>

using u16 = unsigned short;
using u32 = unsigned int;
using bf16x8 = __attribute__((ext_vector_type(8))) __bf16;
using f32x4 = __attribute__((ext_vector_type(4))) float;
using u32x4 = __attribute__((ext_vector_type(4))) u32;
using u32x2 = __attribute__((ext_vector_type(2))) u32;

__device__ __forceinline__ u16 f2bf(float f) {
  union { float f; u32 i; } x; x.f = f;
  u32 r = x.i + 0x7FFFu + ((x.i >> 16) & 1u);
  return (u16)(r >> 16);
}
__device__ __forceinline__ float bf2f(u16 u) {
  union { u32 i; float f; } x; x.i = (u32)u << 16; return x.f;
}
__device__ __forceinline__ float fast_tanh(float x) {
  float e = __expf(2.0f * x);
  return 1.0f - 2.0f / (e + 1.0f);
}

// ---------------- fp32 -> bf16 bulk convert ----------------
__global__ void cvt_bf16(const float* __restrict__ src, u16* __restrict__ dst, int n) {
  int i = (blockIdx.x * 256 + threadIdx.x) * 8;
  if (i + 8 <= n) {
    float4 a = *(const float4*)(src + i), b = *(const float4*)(src + i + 4);
    u16 t[8] = {f2bf(a.x), f2bf(a.y), f2bf(a.z), f2bf(a.w),
                f2bf(b.x), f2bf(b.y), f2bf(b.z), f2bf(b.w)};
    *(uint4*)(dst + i) = *(uint4*)t;
  }
}

// ---------------- boxesT[i][b][f] = tanh(inp[b][i]@Wb^T + bb) ----------------
__global__ __launch_bounds__(256) void box_allT(const float* __restrict__ inp,
    const float* __restrict__ Wb, const float* __restrict__ bb, u16* __restrict__ boxesT) {
  int b = blockIdx.x, t = threadIdx.x;
  __shared__ float sin_[64][12];
  for (int idx = t; idx < 768; idx += 256) sin_[idx / 12][idx % 12] = inp[(long)b * 768 + idx];
  int f0 = (t & 127) * 4, hf = t >> 7;
  float w[4][12], bz[4];
#pragma unroll
  for (int r = 0; r < 4; ++r) {
    bz[r] = bb[f0 + r];
#pragma unroll
    for (int q = 0; q < 12; ++q) w[r][q] = Wb[(f0 + r) * 12 + q];
  }
  __syncthreads();
  for (int i = hf; i < 64; i += 2) {
    float a[4] = {bz[0], bz[1], bz[2], bz[3]};
#pragma unroll
    for (int q = 0; q < 12; ++q) {
      float x = sin_[i][q];
#pragma unroll
      for (int r = 0; r < 4; ++r) a[r] += x * w[r][q];
    }
    u16 p[4];
#pragma unroll
    for (int r = 0; r < 4; ++r) p[r] = f2bf(fast_tanh(a[r]));
    __builtin_nontemporal_store(*(u32x2*)p, (u32x2*)&boxesT[((long)i * 2048 + b) * 512 + f0]);
  }
}

// ======== chain kernel: LDS-staged weights, dbuf pipeline ========
// H pass: C[16x1024] += A(16x512) @ W^T, W in [1024][512]. Tiles: wave w owns
// cols nt*128 + w*16 + l16 (nt=0..7). Chunks hc = kc*2+h: rows [h*512,+512),
// k [kc*32,+32): staged [512][36]-padded, dbuf, 1 barrier/chunk.
__device__ __forceinline__ void h_pass(
    const u16* __restrict__ W, const u16* sABf, u16* sWf, f32x4* C,
    int w16, int l16, int qq, int rR, int rQ) {
  const long gb = (long)rR * 512 + rQ * 8;
  const int wbase = rR * 36 + rQ * 8;
  const int rdd = 128 * 36;
  uint4 R0[4], R1[4];
#pragma unroll
  for (int rd = 0; rd < 4; ++rd) R0[rd] = *(const uint4*)(W + gb + rd * 65536);
#pragma unroll
  for (int rd = 0; rd < 4; ++rd) R1[rd] = *(const uint4*)(W + gb + 262144 + rd * 65536);
#pragma unroll
  for (int rd = 0; rd < 4; ++rd) *(uint4*)&sWf[rd * rdd + wbase] = R0[rd];
  __syncthreads();
  const int bb = (l16 + w16) * 36 + qq * 8;
  for (int hcp = 0; hcp < 16; ++hcp) {
    const int hc0 = hcp * 2;
    // even (h=0, buf0)
    if (hc0 + 2 < 32) {
      const long o = gb + (long)((hcp + 1) * 32);
#pragma unroll
      for (int rd = 0; rd < 4; ++rd) R0[rd] = *(const uint4*)(W + o + rd * 65536);
    }
    bf16x8 af = *(const bf16x8*)&sABf[l16 * 520 + hcp * 32 + qq * 8];
#pragma unroll
    for (int j = 0; j < 4; ++j) {
      bf16x8 b = *(const bf16x8*)&sWf[j * rdd + bb];
      C[j] = __builtin_amdgcn_mfma_f32_16x16x32_bf16(af, b, C[j], 0, 0, 0);
    }
#pragma unroll
    for (int rd = 0; rd < 4; ++rd) *(uint4*)&sWf[18432 + rd * rdd + wbase] = R1[rd];
    __syncthreads();
    // odd (h=1, buf1)
    if (hc0 + 3 < 32) {
      const long o = gb + 262144 + (long)((hcp + 1) * 32);
#pragma unroll
      for (int rd = 0; rd < 4; ++rd) R1[rd] = *(const uint4*)(W + o + rd * 65536);
    }
#pragma unroll
    for (int j = 0; j < 4; ++j) {
      bf16x8 b = *(const bf16x8*)&sWf[18432 + j * rdd + bb];
      C[4 + j] = __builtin_amdgcn_mfma_f32_16x16x32_bf16(af, b, C[4 + j], 0, 0, 0);
    }
    if (hc0 + 2 < 32) {
#pragma unroll
      for (int rd = 0; rd < 4; ++rd) *(uint4*)&sWf[rd * rdd + wbase] = R0[rd];
    }
    __syncthreads();
  }
}

// P pass: D[16x512] = H(16x1024) @ W^T, W in [512][1024]. Wave w owns cols
// nt*128 + w*16 + l16 (nt=0..3). 32 chunks kc: all 512 rows, k [kc*32,+32).
__device__ __forceinline__ void p_pass(
    const u16* __restrict__ W, const u16* sHf, u16* sWf, f32x4* D,
    int w16, int l16, int qq, int rR, int rQ) {
  const long gb = (long)rR * 1024 + rQ * 8;
  const int wbase = rR * 36 + rQ * 8;
  const int rdd = 128 * 36;
  uint4 R0[4], R1[4];
#pragma unroll
  for (int rd = 0; rd < 4; ++rd) R0[rd] = *(const uint4*)(W + gb + rd * 131072);
#pragma unroll
  for (int rd = 0; rd < 4; ++rd) R1[rd] = *(const uint4*)(W + gb + 32 + rd * 131072);
#pragma unroll
  for (int rd = 0; rd < 4; ++rd) *(uint4*)&sWf[rd * rdd + wbase] = R0[rd];
  __syncthreads();
  const int bb = (l16 + w16) * 36 + qq * 8;
  for (int kp = 0; kp < 16; ++kp) {
    const int k0 = kp * 2;
    if (k0 + 2 < 32) {
      const long o = gb + (long)((k0 + 2) * 32);
#pragma unroll
      for (int rd = 0; rd < 4; ++rd) R0[rd] = *(const uint4*)(W + o + rd * 131072);
    }
    bf16x8 af = *(const bf16x8*)&sHf[l16 * 1032 + k0 * 32 + qq * 8];
#pragma unroll
    for (int j = 0; j < 4; ++j) {
      bf16x8 b = *(const bf16x8*)&sWf[j * rdd + bb];
      D[j] = __builtin_amdgcn_mfma_f32_16x16x32_bf16(af, b, D[j], 0, 0, 0);
    }
#pragma unroll
    for (int rd = 0; rd < 4; ++rd) *(uint4*)&sWf[18432 + rd * rdd + wbase] = R1[rd];
    __syncthreads();
    if (k0 + 3 < 32) {
      const long o = gb + (long)((k0 + 3) * 32);
#pragma unroll
      for (int rd = 0; rd < 4; ++rd) R1[rd] = *(const uint4*)(W + o + rd * 131072);
    }
    bf16x8 af2 = *(const bf16x8*)&sHf[l16 * 1032 + (k0 + 1) * 32 + qq * 8];
#pragma unroll
    for (int j = 0; j < 4; ++j) {
      bf16x8 b = *(const bf16x8*)&sWf[18432 + j * rdd + bb];
      D[j] = __builtin_amdgcn_mfma_f32_16x16x32_bf16(af2, b, D[j], 0, 0, 0);
    }
    if (k0 + 2 < 32) {
#pragma unroll
      for (int rd = 0; rd < 4; ++rd) *(uint4*)&sWf[rd * rdd + wbase] = R0[rd];
    }
    __syncthreads();
  }
}

__global__ __launch_bounds__(512, 1) void chain_kernel(
    const u16* __restrict__ boxesT,
    const u16* __restrict__ Wl, const u16* __restrict__ Wr,
    const u16* __restrict__ Ws,
    const u16* __restrict__ Sl, const u16* __restrict__ Ss,
    const float* __restrict__ bl, const float* __restrict__ bs,
    const float* __restrict__ sbl, const float* __restrict__ sbr,
    const float* __restrict__ sbs, const float* __restrict__ SrF,
    const float* __restrict__ sym, float* __restrict__ outF,
    u32* __restrict__ fence) {
  __shared__ u16 sA[16][520];     // acc  (A operand, K=512)
  __shared__ u16 sB[16][520];     // box  (A operand, K=512)
  __shared__ u16 sH[16][1032];    // h    (A operand, K=1024)
  __shared__ float sSym[16][8];
  __shared__ u16 sW[2 * 512 * 36];  // staged weight chunks, dbuf, padded rows

  const int tid = threadIdx.x, lane = tid & 63, w = tid >> 6;
  const int qq = lane >> 4, l16 = lane & 15, w16 = w << 4;
  const int m0 = blockIdx.x * 16;
  const int rR = tid >> 2, rQ = tid & 3;           // stage row / quad
  const int ir = tid >> 5, ic = (tid & 31) * 16;   // init 16x512 slice

  u16* sWf = &sW[0];
  const u16* sAf = &sA[0][0];
  const u16* sBf = &sB[0][0];
  const u16* sHf = &sH[0][0];

  // init: acc <- boxesT[63], box <- boxesT[62]
  {
    const u16* sa = boxesT + ((long)63 * 2048 + m0) * 512;
    const u16* sb = boxesT + ((long)62 * 2048 + m0) * 512;
    *(u32x4*)&sA[ir][ic]     = __builtin_nontemporal_load((const u32x4*)&sa[(long)ir * 512 + ic]);
    *(u32x4*)&sA[ir][ic + 8] = __builtin_nontemporal_load((const u32x4*)&sa[(long)ir * 512 + ic + 8]);
    *(u32x4*)&sB[ir][ic]     = __builtin_nontemporal_load((const u32x4*)&sb[(long)ir * 512 + ic]);
    *(u32x4*)&sB[ir][ic + 8] = __builtin_nontemporal_load((const u32x4*)&sb[(long)ir * 512 + ic + 8]);
  }
  __syncthreads();

  for (int t = 0; t < 79; ++t) {
    const bool symPhase = (t >= 63);
    if (symPhase) {
      int symp = 78 - t;
      if (tid < 128) sSym[tid >> 3][tid & 7] = sym[((long)(m0 + (tid >> 3)) * 16 + symp) * 8 + (tid & 7)];
      __syncthreads();
    }
    // prefetch next box slice early (arrives during H phase)
    u32x4 bv0, bv1;
    const bool pf = (t < 62);
    if (pf) {
      const u16* src = boxesT + ((long)(61 - t) * 2048 + m0) * 512;
      bv0 = __builtin_nontemporal_load((const u32x4*)&src[(long)ir * 512 + ic]);
      bv1 = __builtin_nontemporal_load((const u32x4*)&src[(long)ir * 512 + ic + 8]);
    }

    // ================= H phase =================
    f32x4 C[8];
#pragma unroll
    for (int i = 0; i < 8; ++i) C[i] = (f32x4){0.f, 0.f, 0.f, 0.f};

    h_pass(symPhase ? Sl : Wl, sAf, sWf, C, w16, l16, qq, rR, rQ);
    if (!symPhase) h_pass(Wr, sBf, sWf, C, w16, l16, qq, rR, rQ);

    // ---- epilogue H -> sH ----
    if (!symPhase) {
#pragma unroll
      for (int nt = 0; nt < 8; ++nt) {
        int col = nt * 128 + w16 + l16;
        float bn = bl[col];
#pragma unroll
        for (int r = 0; r < 4; ++r)
          sH[qq * 4 + r][col] = f2bf(fast_tanh(C[nt][r] + bn));
      }
    } else {
      float symv[4][8];
#pragma unroll
      for (int r = 0; r < 4; ++r)
#pragma unroll
        for (int k = 0; k < 8; ++k) symv[r][k] = sSym[qq * 4 + r][k];
#pragma unroll
      for (int nt = 0; nt < 8; ++nt) {
        int col = nt * 128 + w16 + l16;
        float bn = sbl[col] + sbr[col];
        float sr[8];
        *(float4*)&sr[0] = *(const float4*)&SrF[(long)col * 8];
        *(float4*)&sr[4] = *(const float4*)&SrF[(long)col * 8 + 4];
#pragma unroll
        for (int r = 0; r < 4; ++r) {
          float v = C[nt][r] + bn;
#pragma unroll
          for (int k = 0; k < 8; ++k) v += symv[r][k] * sr[k];
          sH[qq * 4 + r][col] = f2bf(fast_tanh(v));
        }
      }
    }
    // NOTE: no explicit barrier needed here — p_pass prologue barrier orders
    // sH writes before its first MFMA read, and sW buf0 writes are disjoint
    // from H's last buf1 reads (all waves passed H's final barrier).

    // ================= P phase =================
    f32x4 D[4];
#pragma unroll
    for (int i = 0; i < 4; ++i) D[i] = (f32x4){0.f, 0.f, 0.f, 0.f};
    p_pass(symPhase ? Ss : Ws, sHf, sWf, D, w16, l16, qq, rR, rQ);

    // box slice for next step (all sB readers finished before p_pass barriers)
    if (pf) {
      *(u32x4*)&sB[ir][ic] = bv0;
      *(u32x4*)&sB[ir][ic + 8] = bv1;
    }

    // ---- epilogue P -> sA (+out) ----
    const float* b2 = symPhase ? sbs : bs;
    const bool last = (t == 78);
#pragma unroll
    for (int nt = 0; nt < 4; ++nt) {
      int f0 = nt * 128 + w16 + l16;
      float bn = b2[f0];
#pragma unroll
      for (int r = 0; r < 4; ++r) {
        int m = qq * 4 + r;
        float a = fast_tanh(D[nt][r] + bn);
        sA[m][f0] = f2bf(a);
        if (last) outF[(long)(m0 + m) * 512 + f0] = a;
      }
    }

    // ---- per-step drift fence (RELAXED, perf-only) ----
    if (t < 78) {
      __syncthreads();
      if (tid == 0) {
        __hip_atomic_fetch_add(&fence[t], 1u, __ATOMIC_RELAXED, __HIP_MEMORY_SCOPE_AGENT);
        while (__hip_atomic_load(&fence[t], __ATOMIC_RELAXED, __HIP_MEMORY_SCOPE_AGENT) < 128u)
          __builtin_amdgcn_s_sleep(2);
      }
      __syncthreads();
    }
  }
}

// ================= fallback kernels (small-ws path) =================
__global__ __launch_bounds__(256) void box_all_v2(const float* __restrict__ inp,
    const float* __restrict__ Wb, const float* __restrict__ bb, u16* __restrict__ boxes) {
  int b = blockIdx.x, t = threadIdx.x;
  __shared__ float sin_[64][12];
  for (int idx = t; idx < 768; idx += 256) sin_[idx / 12][idx % 12] = inp[(long)b * 768 + idx];
  const int f0 = t * 2;
  float w0[12], w1[12];
#pragma unroll
  for (int q = 0; q < 12; ++q) { w0[q] = Wb[f0 * 12 + q]; w1[q] = Wb[(f0 + 1) * 12 + q]; }
  float b0 = bb[f0], b1 = bb[f0 + 1];
  __syncthreads();
  for (int i = 0; i < 64; ++i) {
    float a0 = b0, a1 = b1;
#pragma unroll
    for (int q = 0; q < 12; ++q) { float x = sin_[i][q]; a0 += x * w0[q]; a1 += x * w1[q]; }
    u32 pk = (u32)f2bf(fast_tanh(a0)) | ((u32)f2bf(fast_tanh(a1)) << 16);
    *(u32*)&boxes[(((long)b * 64 + i) * 512) + f0] = pk;
  }
}

__global__ __launch_bounds__(256) void gemm64(
    const u16* __restrict__ A1, int lda1,
    const u16* __restrict__ W1b, const float* __restrict__ W1f, int K1,
    const u16* __restrict__ A2, int lda2,
    const u16* __restrict__ W2b, const float* __restrict__ W2f, int K2,
    const float* __restrict__ bias,
    const float* __restrict__ symS, const float* __restrict__ Srw, const float* __restrict__ sbr,
    int doTanh, int outMode,
    u16* __restrict__ Cb, float* __restrict__ Cf, int N) {
  __shared__ u16 As[64][72];
  __shared__ u16 Bs[64][72];
  const int tid = threadIdx.x;
  const int lane = tid & 63, w = tid >> 6;
  const int wr = w >> 1, wc = w & 1;
  const int quad = lane >> 4, l16 = lane & 15;
  const int m0 = blockIdx.y * 64, n0 = blockIdx.x * 64;
  const int srow = tid >> 2, scol = (tid & 3) * 16;
  f32x4 acc[2][2];
#pragma unroll
  for (int i = 0; i < 2; ++i)
#pragma unroll
    for (int j = 0; j < 2; ++j) acc[i][j] = (f32x4){0.f, 0.f, 0.f, 0.f};
#pragma unroll
  for (int pair = 0; pair < 2; ++pair) {
    const u16* A = pair ? A2 : A1;
    const u16* Wb_ = pair ? W2b : W1b;
    const float* Wf_ = pair ? W2f : W1f;
    const int lda = pair ? lda2 : lda1;
    const int K = pair ? K2 : K1;
    if (K == 0) continue;
    for (int k0 = 0; k0 < K; k0 += 64) {
      const u16* ap = &A[(long)(m0 + srow) * lda + k0 + scol];
      uint4 av0 = *(const uint4*)ap;
      uint4 av1 = *(const uint4*)(ap + 8);
      uint4 bv0, bv1;
      if (Wb_) {
        const u16* wp = &Wb_[(long)(n0 + srow) * K + k0 + scol];
        bv0 = *(const uint4*)wp;
        bv1 = *(const uint4*)(wp + 8);
      } else {
        const float* wp = &Wf_[(long)(n0 + srow) * K + k0 + scol];
        u16 tv[16];
#pragma unroll
        for (int qq = 0; qq < 16; ++qq) tv[qq] = f2bf(wp[qq]);
        bv0 = ((uint4*)tv)[0];
        bv1 = ((uint4*)tv)[1];
      }
      __syncthreads();
      *(uint4*)&As[srow][scol] = av0;
      *(uint4*)&As[srow][scol + 8] = av1;
      *(uint4*)&Bs[srow][scol] = bv0;
      *(uint4*)&Bs[srow][scol + 8] = bv1;
      __syncthreads();
      bf16x8 af[2][2], bfv[2][2];
#pragma unroll
      for (int kk = 0; kk < 2; ++kk) {
#pragma unroll
        for (int i = 0; i < 2; ++i)
          af[i][kk] = *(const bf16x8*)&As[wr * 32 + i * 16 + l16][kk * 32 + quad * 8];
#pragma unroll
        for (int j = 0; j < 2; ++j)
          bfv[j][kk] = *(const bf16x8*)&Bs[wc * 32 + j * 16 + l16][kk * 32 + quad * 8];
      }
#pragma unroll
      for (int kk = 0; kk < 2; ++kk)
#pragma unroll
        for (int i = 0; i < 2; ++i)
#pragma unroll
          for (int j = 0; j < 2; ++j)
            acc[i][j] = __builtin_amdgcn_mfma_f32_16x16x32_bf16(af[i][kk], bfv[j][kk], acc[i][j], 0, 0, 0);
    }
  }
#pragma unroll
  for (int j = 0; j < 2; ++j) {
    const int n = n0 + wc * 32 + j * 16 + l16;
    float bn = bias ? bias[n] : 0.0f;
    float srn[8];
    if (symS) {
      bn += sbr[n];
#pragma unroll
      for (int qq = 0; qq < 8; ++qq) srn[qq] = Srw[n * 8 + qq];
    }
#pragma unroll
    for (int i = 0; i < 2; ++i) {
#pragma unroll
      for (int r = 0; r < 4; ++r) {
        const int m = m0 + wr * 32 + i * 16 + quad * 4 + r;
        float v = acc[i][j][r] + bn;
        if (symS) {
#pragma unroll
          for (int qq = 0; qq < 8; ++qq) v += symS[(long)m * 128 + qq] * srn[qq];
        }
        if (doTanh) v = fast_tanh(v);
        if (outMode == 0) Cb[(long)m * N + n] = f2bf(v);
        else Cf[(long)m * N + n] = v;
      }
    }
  }
}

extern "C" void kernel_launch(void* const* d_in, const int* in_sizes, int n_in,
                              void* d_out, int out_size, void* d_ws, size_t ws_size,
                              hipStream_t stream) {
  const float* inp = (const float*)d_in[0];
  const float* sym = (const float*)d_in[1];
  const float* Wb  = (const float*)d_in[3];
  const float* bb  = (const float*)d_in[4];
  const float* Wl  = (const float*)d_in[5];
  const float* bl  = (const float*)d_in[6];
  const float* Wr  = (const float*)d_in[7];
  const float* Ws  = (const float*)d_in[8];
  const float* bs  = (const float*)d_in[9];
  const float* Sl  = (const float*)d_in[10];
  const float* sbl = (const float*)d_in[11];
  const float* Sr  = (const float*)d_in[12];
  const float* sbr = (const float*)d_in[13];
  const float* Ss  = (const float*)d_in[14];
  const float* sbs = (const float*)d_in[15];

  const long B = 2048, NB = 64, F = 512, H = 1024;
  const long WE = 524288;
  u16* ws = (u16*)d_ws;
  dim3 blk(256);

  // fused path: 5 bf16 weights + boxesT + fence (~139.5 MB)
  const size_t baseU16 = (size_t)5 * WE + (size_t)64 * B * F;
  const size_t needNew = baseU16 * 2 + 512;

  if (ws_size >= needNew) {
    u16* WlB = ws;
    u16* WrB = WlB + WE;
    u16* WsB = WrB + WE;
    u16* SlB = WsB + WE;
    u16* SsB = SlB + WE;
    u16* boxesT = SsB + WE;                  // [64][2048][512]
    u32* fence = (u32*)(ws + baseU16);       // 79 step counters

    (void)hipMemsetAsync(fence, 0, 80 * sizeof(u32), stream);
    cvt_bf16<<<WE / 2048, blk, 0, stream>>>(Wl, WlB, (int)WE);
    cvt_bf16<<<WE / 2048, blk, 0, stream>>>(Wr, WrB, (int)WE);
    cvt_bf16<<<WE / 2048, blk, 0, stream>>>(Ws, WsB, (int)WE);
    cvt_bf16<<<WE / 2048, blk, 0, stream>>>(Sl, SlB, (int)WE);
    cvt_bf16<<<WE / 2048, blk, 0, stream>>>(Ss, SsB, (int)WE);
    box_allT<<<B, blk, 0, stream>>>(inp, Wb, bb, boxesT);
    chain_kernel<<<128, dim3(512), 0, stream>>>(boxesT, WlB, WrB, WsB, SlB, SsB,
                                                bl, bs, sbl, sbr, sbs, Sr, sym,
                                                (float*)d_out, fence);
  } else {
    // fallback: bf16 weights if they fit, else fp32 staging
    dim3 gH(16, 32), gP(8, 32);
    const size_t szW = 5 * WE * 2, szBoxes = (size_t)B * NB * F * 2;
    const size_t szH = (size_t)B * H * 2, szAcc = (size_t)B * F * 2;
    const size_t needT2 = szW + szBoxes + szH + szAcc;
    const size_t needT3 = szBoxes + szH + szAcc;
    int tier = (ws_size >= needT2) ? 2 : (ws_size >= needT3) ? 3 : 4;
    u16 *WlB = nullptr, *WrB = nullptr, *WsB = nullptr, *SlB = nullptr, *SsB = nullptr;
    const float *WlF = Wl, *WrF = Wr, *WsF = Ws, *SlF = Sl, *SsF = Ss;
    u16* p = ws;
    if (tier == 2) {
      WlB = p; WrB = p + WE; WsB = p + 2 * WE; SlB = p + 3 * WE; SsB = p + 4 * WE;
      p += 5 * WE;
      cvt_bf16<<<WE / 2048, blk, 0, stream>>>(Wl, WlB, (int)WE);
      cvt_bf16<<<WE / 2048, blk, 0, stream>>>(Wr, WrB, (int)WE);
      cvt_bf16<<<WE / 2048, blk, 0, stream>>>(Ws, WsB, (int)WE);
      cvt_bf16<<<WE / 2048, blk, 0, stream>>>(Sl, SlB, (int)WE);
      cvt_bf16<<<WE / 2048, blk, 0, stream>>>(Ss, SsB, (int)WE);
      WlF = WrF = WsF = SlF = SsF = nullptr;
    }
    u16* boxes = p;
    p += B * NB * F;
    u16* hBuf = p; p += B * H;
    u16* accBuf = p;
    box_all_v2<<<B, blk, 0, stream>>>(inp, Wb, bb, boxes);
    const u16* curA = boxes + 63 * 512;
    int curLda = (int)(NB * F);
    for (int bp = 62; bp >= 0; --bp) {
      gemm64<<<gH, blk, 0, stream>>>(curA, curLda, WlB, WlF, 512,
                                     boxes + (long)bp * 512, (int)(NB * F), WrB, WrF, 512,
                                     bl, nullptr, nullptr, nullptr, 1, 0, hBuf, nullptr, 1024);
      gemm64<<<gP, blk, 0, stream>>>(hBuf, 1024, WsB, WsF, 1024,
                                     nullptr, 0, nullptr, nullptr, 0,
                                     bs, nullptr, nullptr, nullptr, 1, 0, accBuf, nullptr, 512);
      curA = accBuf; curLda = 512;
    }
    for (int symp = 15; symp >= 0; --symp) {
      gemm64<<<gH, blk, 0, stream>>>(accBuf, 512, SlB, SlF, 512,
                                     nullptr, 0, nullptr, nullptr, 0,
                                     sbl, sym + symp * 8, Sr, sbr, 1, 0, hBuf, nullptr, 1024);
      int om = (symp == 0) ? 1 : 0;
      gemm64<<<gP, blk, 0, stream>>>(hBuf, 1024, SsB, SsF, 1024,
                                     nullptr, 0, nullptr, nullptr, 0,
                                     sbs, nullptr, nullptr, nullptr, 1, om, accBuf, (float*)d_out, 512);
    }
  }
  (void)in_sizes; (void)n_in; (void)out_size;
}

// Round 6
// 3806.902 us; speedup vs baseline: 4.2443x; 4.2443x over previous
//
#include <hip/hip_runtime.h>
#include <cmath>

using u16 = unsigned short;
using u32 = unsigned int;
using u64 = unsigned long long;
using bf16x8 = __attribute__((ext_vector_type(8))) __bf16;
using f32x4 = __attribute__((ext_vector_type(4))) float;
using u32x4 = __attribute__((ext_vector_type(4))) u32;
using u32x2 = __attribute__((ext_vector_type(2))) u32;

__device__ __forceinline__ u16 f2bf(float f) {
  union { float f; u32 i; } x; x.f = f;
  u32 r = x.i + 0x7FFFu + ((x.i >> 16) & 1u);
  return (u16)(r >> 16);
}
__device__ __forceinline__ float fast_tanh(float x) {
  float e = __expf(2.0f * x);
  return 1.0f - 2.0f / (e + 1.0f);
}
__device__ __forceinline__ void load_lds16(const u16* g, u16* l) {
  __builtin_amdgcn_global_load_lds((const __attribute__((address_space(1))) u32*)g,
                                   (__attribute__((address_space(3))) u32*)l, 16, 0, 0);
}
// operand-tile byte offset with XOR swizzle (row stride 1024B, bits 4-6 xor'd)
__device__ __forceinline__ int sxo(int row, int kb) {
  return row * 1024 + (kb ^ ((row & 7) << 4));
}

// ---------------- fp32 -> bf16 bulk convert ----------------
__global__ void cvt_bf16(const float* __restrict__ src, u16* __restrict__ dst, int n) {
  int i = (blockIdx.x * 256 + threadIdx.x) * 8;
  if (i + 8 <= n) {
    float4 a = *(const float4*)(src + i), b = *(const float4*)(src + i + 4);
    u16 t[8] = {f2bf(a.x), f2bf(a.y), f2bf(a.z), f2bf(a.w),
                f2bf(b.x), f2bf(b.y), f2bf(b.z), f2bf(b.w)};
    *(uint4*)(dst + i) = *(uint4*)t;
  }
}

// ---------------- boxesT[i][b][f] = tanh(inp[b][i]@Wb^T + bb) ----------------
__global__ __launch_bounds__(256) void box_allT(const float* __restrict__ inp,
    const float* __restrict__ Wb, const float* __restrict__ bb, u16* __restrict__ boxesT) {
  int b = blockIdx.x, t = threadIdx.x;
  __shared__ float sin_[64][12];
  for (int idx = t; idx < 768; idx += 256) sin_[idx / 12][idx % 12] = inp[(long)b * 768 + idx];
  int f0 = (t & 127) * 4, hf = t >> 7;
  float w[4][12], bz[4];
#pragma unroll
  for (int r = 0; r < 4; ++r) {
    bz[r] = bb[f0 + r];
#pragma unroll
    for (int q = 0; q < 12; ++q) w[r][q] = Wb[(f0 + r) * 12 + q];
  }
  __syncthreads();
  for (int i = hf; i < 64; i += 2) {
    float a[4] = {bz[0], bz[1], bz[2], bz[3]};
#pragma unroll
    for (int q = 0; q < 12; ++q) {
      float x = sin_[i][q];
#pragma unroll
      for (int r = 0; r < 4; ++r) a[r] += x * w[r][q];
    }
    u16 p[4];
#pragma unroll
    for (int r = 0; r < 4; ++r) p[r] = f2bf(fast_tanh(a[r]));
    __builtin_nontemporal_store(*(u32x2*)p, (u32x2*)&boxesT[((long)i * 2048 + b) * 512 + f0]);
  }
}

// ======== chain2: N-split cooperative chain ========
// 256 blocks = 32 row-groups (64 rows) x 8 col-slices. Per step:
//   H: h[64 x 128c] = tanh(acc@Wl_c^T + box@Wr_c^T + bl)   (sym: Sl_c + sym@Sr^T)
//   fence; P: acc[64 x 64c] = tanh(h@Ws_c^T + bs); fence.
// Exchange acc/h via relaxed AGENT atomics (IC-coherent, no L2 invalidation).
// Weight slices streamed via depth-3 global_load_lds pipeline, raw s_barrier +
// counted vmcnt (never 0 in loop). All LDS tiles XOR-swizzled.
__global__ __launch_bounds__(512, 1) void chain2(
    const u16* __restrict__ boxesT,
    const u16* __restrict__ Wl, const u16* __restrict__ Wr, const u16* __restrict__ Ws,
    const u16* __restrict__ Sl, const u16* __restrict__ Ss,
    const float* __restrict__ bl, const float* __restrict__ bs,
    const float* __restrict__ sbl, const float* __restrict__ sbr,
    const float* __restrict__ sbs, const float* __restrict__ SrF,
    const float* __restrict__ sym,
    u16* __restrict__ accG, u16* __restrict__ hG, float* __restrict__ outF,
    u32* __restrict__ fence) {
  __shared__ u16 sX0[64 * 512];   // acc (H) / h lo-half (P); epilogue: pack+sym overlay
  __shared__ u16 sX1[64 * 512];   // box (H) / h hi-half (P)
  __shared__ u16 sW[3 * 4096];    // 3 x 8KB weight chunk bufs

  const int tid = threadIdx.x, lane = tid & 63, w = tid >> 6;
  const int qq = lane >> 4, l16 = lane & 15;
  const int wr2 = w >> 1, wc2 = w & 1;
  const int bid = blockIdx.x;
  const int r = bid & 31, c = bid >> 5;  // bid%8 = r%8 -> same-r blocks share XCD
  const int m0 = r * 64;
  char* sX0b = (char*)sX0;
  char* sX1b = (char*)sX1;
  u64* hU = (u64*)hG;
  u64* aU = (u64*)accG;

  const int arow = wr2 * 16 + l16;
  const int aX = (arow & 7) << 4;

  // H-chunk gll source precompute: chunk layout [128 n][32 k], swizzle bits 4-5
  const int gn = tid >> 2;
  const int gkb = ((tid & 3) * 16) ^ (((gn >> 1) & 3) << 4);
  // P-chunk: layout [64 n][64 k], swizzle bits 4-6
  const int pr = tid >> 3;
  const int pkb = ((tid & 7) * 16) ^ ((pr & 7) << 4);

  int hb[4];
#pragma unroll
  for (int j = 0; j < 4; ++j) {
    int nl = wc2 * 64 + j * 16 + l16;
    hb[j] = nl * 64 + ((qq * 16) ^ (((nl >> 1) & 3) << 4));
  }
  int pb[2][2];
#pragma unroll
  for (int j = 0; j < 2; ++j)
#pragma unroll
    for (int s1 = 0; s1 < 2; ++s1) {
      int rl = wc2 * 32 + j * 16 + l16;
      pb[j][s1] = rl * 128 + ((s1 * 64 + qq * 16) ^ ((rl & 7) << 4));
    }

  for (int t = 0; t < 79; ++t) {
    const bool symPhase = (t >= 63);
    const bool last = (t == 78);
    // ================= H phase =================
    // stage acc -> sX0
    if (t == 0) {
      const u16* src = boxesT + ((long)63 * 2048 + m0) * 512;
#pragma unroll
      for (int i = 0; i < 8; ++i) {
        int idx = i * 512 + tid, row = idx >> 6, u = idx & 63;
        *(u32x4*)(sX0b + sxo(row, u * 16)) = *(const u32x4*)(src + (long)row * 512 + u * 8);
      }
    } else {
#pragma unroll
      for (int i = 0; i < 16; ++i) {
        int idx = i * 512 + tid, row = idx >> 7, u = idx & 127;
        u64 v = __hip_atomic_load(aU + (long)(m0 + row) * 128 + u,
                                  __ATOMIC_RELAXED, __HIP_MEMORY_SCOPE_AGENT);
        *(u64*)(sX0b + sxo(row, u * 8)) = v;
      }
    }
    if (!symPhase) {  // stage box -> sX1 (plain: share via XCD L2)
      const u16* src = boxesT + ((long)(62 - t) * 2048 + m0) * 512;
#pragma unroll
      for (int i = 0; i < 8; ++i) {
        int idx = i * 512 + tid, row = idx >> 6, u = idx & 63;
        *(u32x4*)(sX1b + sxo(row, u * 16)) = *(const u32x4*)(src + (long)row * 512 + u * 8);
      }
    }
    __syncthreads();  // drains vmcnt -> clean baseline for counted pipeline

    const u16* WA = symPhase ? Sl : Wl;
    const int nch = symPhase ? 16 : 32;
    const long gWoff = ((long)(c * 128 + gn)) * 512 + (gkb >> 1);

    f32x4 C[4];
#pragma unroll
    for (int j = 0; j < 4; ++j) C[j] = (f32x4){0.f, 0.f, 0.f, 0.f};

    {
      // prologue: chunks 0,1 into bufs 0,1
      {
        int u0 = 0, u1 = symPhase ? 1 : 0;
        load_lds16(WA + gWoff + u0 * 32, sW + 0 * 4096 + tid * 8);
        const u16* s1p = symPhase ? (WA + gWoff + u1 * 32 + 32) : (Wr + gWoff);
        if (symPhase) load_lds16(WA + gWoff + 32, sW + 1 * 4096 + tid * 8);
        else          load_lds16(Wr + gWoff,      sW + 1 * 4096 + tid * 8);
        (void)s1p;
      }
      int cb = 0, nb = 2;
      for (int ci = 0; ci < nch; ++ci) {
        if (ci + 2 < nch) {
          int cj = ci + 2;
          int u = symPhase ? cj : (cj >> 1);
          if (symPhase || !(cj & 1)) load_lds16(WA + gWoff + u * 32, sW + nb * 4096 + tid * 8);
          else                       load_lds16(Wr + gWoff + u * 32, sW + nb * 4096 + tid * 8);
        }
        if (ci + 2 < nch)      asm volatile("s_waitcnt vmcnt(2)" ::: "memory");
        else if (ci + 1 < nch) asm volatile("s_waitcnt vmcnt(1)" ::: "memory");
        else                   asm volatile("s_waitcnt vmcnt(0)" ::: "memory");
        __builtin_amdgcn_s_barrier();
        asm volatile("" ::: "memory");
        {
          const char* bufb = (const char*)sW + cb * 8192;
          int u = symPhase ? ci : (ci >> 1);
          const char* ab = (!symPhase && (ci & 1)) ? sX1b : sX0b;
          int akb = (u * 64 + qq * 16) ^ aX;
          bf16x8 af = *(const bf16x8*)(ab + arow * 1024 + akb);
#pragma unroll
          for (int j = 0; j < 4; ++j)
            C[j] = __builtin_amdgcn_mfma_f32_16x16x32_bf16(
                af, *(const bf16x8*)(bufb + hb[j]), C[j], 0, 0, 0);
        }
        __builtin_amdgcn_s_barrier();
        asm volatile("" ::: "memory");
        cb = (cb == 2) ? 0 : cb + 1;
        nb = (nb == 2) ? 0 : nb + 1;
      }
    }

    // ---- H epilogue: tanh(+bias [+sym@Sr]) -> pack -> atomic store to hG ----
    if (symPhase) {
      float* sSymF = (float*)(sX0b + 20480);
      int symp = 78 - t;
      sSymF[tid] = sym[((long)(m0 + (tid >> 3)) * 16 + symp) * 8 + (tid & 7)];
      __syncthreads();
    }
    u16* sP = (u16*)sX0b;
#pragma unroll
    for (int j = 0; j < 4; ++j) {
      int lcol = wc2 * 64 + j * 16 + l16;
      int col = c * 128 + lcol;
      if (!symPhase) {
        float bn = bl[col];
#pragma unroll
        for (int rr = 0; rr < 4; ++rr) {
          int m = wr2 * 16 + qq * 4 + rr;
          sP[m * 136 + lcol] = f2bf(fast_tanh(C[j][rr] + bn));
        }
      } else {
        float bn = sbl[col] + sbr[col];
        float sr[8];
        *(float4*)&sr[0] = *(const float4*)&SrF[(long)col * 8];
        *(float4*)&sr[4] = *(const float4*)&SrF[(long)col * 8 + 4];
        const float* sSymF = (const float*)(sX0b + 20480);
#pragma unroll
        for (int rr = 0; rr < 4; ++rr) {
          int m = wr2 * 16 + qq * 4 + rr;
          float v = C[j][rr] + bn;
          const float* sv = sSymF + m * 8;
#pragma unroll
          for (int k = 0; k < 8; ++k) v += sv[k] * sr[k];
          sP[m * 136 + lcol] = f2bf(fast_tanh(v));
        }
      }
    }
    __syncthreads();
#pragma unroll
    for (int i = 0; i < 4; ++i) {
      int idx = i * 512 + tid, row = idx >> 5, cu = idx & 31;
      u64 v = *(const u64*)(sX0b + row * 272 + cu * 8);
      __hip_atomic_store(hU + (long)(m0 + row) * 256 + c * 32 + cu, v,
                         __ATOMIC_RELAXED, __HIP_MEMORY_SCOPE_AGENT);
    }
    // ---- fence: all h written ----
    __syncthreads();
    if (tid == 0) {
      __hip_atomic_fetch_add(fence + 2 * t, 1u, __ATOMIC_RELAXED, __HIP_MEMORY_SCOPE_AGENT);
      while (__hip_atomic_load(fence + 2 * t, __ATOMIC_RELAXED, __HIP_MEMORY_SCOPE_AGENT) < 256u)
        __builtin_amdgcn_s_sleep(2);
    }
    __syncthreads();
    asm volatile("" ::: "memory");

    // ================= P phase =================
    // stage h -> sX0 (k<512) / sX1 (k>=512)
    {
      const int u = tid & 255;
      const bool lo = (u < 128);
#pragma unroll
      for (int i = 0; i < 32; ++i) {
        int idx = i * 512 + tid, row = idx >> 8;
        u64 v = __hip_atomic_load(hU + (long)(m0 + row) * 256 + u,
                                  __ATOMIC_RELAXED, __HIP_MEMORY_SCOPE_AGENT);
        if (lo) *(u64*)(sX0b + sxo(row, u * 8)) = v;
        else    *(u64*)(sX1b + sxo(row, (u - 128) * 8)) = v;
      }
    }
    __syncthreads();
    if (last) {  // out writes will alias hG: wait until ALL blocks staged h
      if (tid == 0) {
        __hip_atomic_fetch_add(fence + 158, 1u, __ATOMIC_RELAXED, __HIP_MEMORY_SCOPE_AGENT);
        while (__hip_atomic_load(fence + 158, __ATOMIC_RELAXED, __HIP_MEMORY_SCOPE_AGENT) < 256u)
          __builtin_amdgcn_s_sleep(2);
      }
      __syncthreads();
      asm volatile("" ::: "memory");
    }

    const u16* WP = symPhase ? Ss : Ws;
    const long gPoff = ((long)(c * 64 + pr)) * 1024 + (pkb >> 1);
    f32x4 D[2];
    D[0] = (f32x4){0.f, 0.f, 0.f, 0.f};
    D[1] = (f32x4){0.f, 0.f, 0.f, 0.f};
    {
      load_lds16(WP + gPoff + 0 * 64, sW + 0 * 4096 + tid * 8);
      load_lds16(WP + gPoff + 1 * 64, sW + 1 * 4096 + tid * 8);
      int cb = 0, nb = 2;
      for (int ci = 0; ci < 16; ++ci) {
        if (ci + 2 < 16) load_lds16(WP + gPoff + (ci + 2) * 64, sW + nb * 4096 + tid * 8);
        if (ci + 2 < 16)      asm volatile("s_waitcnt vmcnt(2)" ::: "memory");
        else if (ci + 1 < 16) asm volatile("s_waitcnt vmcnt(1)" ::: "memory");
        else                  asm volatile("s_waitcnt vmcnt(0)" ::: "memory");
        __builtin_amdgcn_s_barrier();
        asm volatile("" ::: "memory");
        {
          const char* bufb = (const char*)sW + cb * 8192;
          const char* ab = (ci < 8) ? sX0b : sX1b;
          int base = (ci & 7) * 128;
#pragma unroll
          for (int s1 = 0; s1 < 2; ++s1) {
            int akb = (base + s1 * 64 + qq * 16) ^ aX;
            bf16x8 af = *(const bf16x8*)(ab + arow * 1024 + akb);
#pragma unroll
            for (int j = 0; j < 2; ++j)
              D[j] = __builtin_amdgcn_mfma_f32_16x16x32_bf16(
                  af, *(const bf16x8*)(bufb + pb[j][s1]), D[j], 0, 0, 0);
          }
        }
        __builtin_amdgcn_s_barrier();
        asm volatile("" ::: "memory");
        cb = (cb == 2) ? 0 : cb + 1;
        nb = (nb == 2) ? 0 : nb + 1;
      }
    }

    // ---- P epilogue ----
    const float* b2 = symPhase ? sbs : bs;
    if (!last) {
#pragma unroll
      for (int j = 0; j < 2; ++j) {
        int lcol = wc2 * 32 + j * 16 + l16;
        float bn = b2[c * 64 + lcol];
#pragma unroll
        for (int rr = 0; rr < 4; ++rr) {
          int m = wr2 * 16 + qq * 4 + rr;
          sP[m * 72 + lcol] = f2bf(fast_tanh(D[j][rr] + bn));
        }
      }
      __syncthreads();
#pragma unroll
      for (int i = 0; i < 2; ++i) {
        int idx = i * 512 + tid, row = idx >> 4, cu = idx & 15;
        u64 v = *(const u64*)(sX0b + row * 144 + cu * 8);
        __hip_atomic_store(aU + (long)(m0 + row) * 128 + c * 16 + cu, v,
                           __ATOMIC_RELAXED, __HIP_MEMORY_SCOPE_AGENT);
      }
      // ---- fence: all acc written ----
      __syncthreads();
      if (tid == 0) {
        __hip_atomic_fetch_add(fence + 2 * t + 1, 1u, __ATOMIC_RELAXED, __HIP_MEMORY_SCOPE_AGENT);
        while (__hip_atomic_load(fence + 2 * t + 1, __ATOMIC_RELAXED, __HIP_MEMORY_SCOPE_AGENT) < 256u)
          __builtin_amdgcn_s_sleep(2);
      }
      __syncthreads();
      asm volatile("" ::: "memory");
    } else {
#pragma unroll
      for (int j = 0; j < 2; ++j) {
        int lcol = wc2 * 32 + j * 16 + l16;
        int col = c * 64 + lcol;
        float bn = b2[col];
#pragma unroll
        for (int rr = 0; rr < 4; ++rr) {
          int m = wr2 * 16 + qq * 4 + rr;
          outF[(long)(m0 + m) * 512 + col] = fast_tanh(D[j][rr] + bn);
        }
      }
    }
  }
}

// ================= fallback kernels (small-ws path) =================
__global__ __launch_bounds__(256) void box_all_v2(const float* __restrict__ inp,
    const float* __restrict__ Wb, const float* __restrict__ bb, u16* __restrict__ boxes) {
  int b = blockIdx.x, t = threadIdx.x;
  __shared__ float sin_[64][12];
  for (int idx = t; idx < 768; idx += 256) sin_[idx / 12][idx % 12] = inp[(long)b * 768 + idx];
  const int f0 = t * 2;
  float w0[12], w1[12];
#pragma unroll
  for (int q = 0; q < 12; ++q) { w0[q] = Wb[f0 * 12 + q]; w1[q] = Wb[(f0 + 1) * 12 + q]; }
  float b0 = bb[f0], b1 = bb[f0 + 1];
  __syncthreads();
  for (int i = 0; i < 64; ++i) {
    float a0 = b0, a1 = b1;
#pragma unroll
    for (int q = 0; q < 12; ++q) { float x = sin_[i][q]; a0 += x * w0[q]; a1 += x * w1[q]; }
    u32 pk = (u32)f2bf(fast_tanh(a0)) | ((u32)f2bf(fast_tanh(a1)) << 16);
    *(u32*)&boxes[(((long)b * 64 + i) * 512) + f0] = pk;
  }
}

__global__ __launch_bounds__(256) void gemm64(
    const u16* __restrict__ A1, int lda1,
    const u16* __restrict__ W1b, const float* __restrict__ W1f, int K1,
    const u16* __restrict__ A2, int lda2,
    const u16* __restrict__ W2b, const float* __restrict__ W2f, int K2,
    const float* __restrict__ bias,
    const float* __restrict__ symS, const float* __restrict__ Srw, const float* __restrict__ sbr,
    int doTanh, int outMode,
    u16* __restrict__ Cb, float* __restrict__ Cf, int N) {
  __shared__ u16 As[64][72];
  __shared__ u16 Bs[64][72];
  const int tid = threadIdx.x;
  const int lane = tid & 63, w = tid >> 6;
  const int wr = w >> 1, wc = w & 1;
  const int quad = lane >> 4, l16 = lane & 15;
  const int m0 = blockIdx.y * 64, n0 = blockIdx.x * 64;
  const int srow = tid >> 2, scol = (tid & 3) * 16;
  f32x4 acc[2][2];
#pragma unroll
  for (int i = 0; i < 2; ++i)
#pragma unroll
    for (int j = 0; j < 2; ++j) acc[i][j] = (f32x4){0.f, 0.f, 0.f, 0.f};
#pragma unroll
  for (int pair = 0; pair < 2; ++pair) {
    const u16* A = pair ? A2 : A1;
    const u16* Wb_ = pair ? W2b : W1b;
    const float* Wf_ = pair ? W2f : W1f;
    const int lda = pair ? lda2 : lda1;
    const int K = pair ? K2 : K1;
    if (K == 0) continue;
    for (int k0 = 0; k0 < K; k0 += 64) {
      const u16* ap = &A[(long)(m0 + srow) * lda + k0 + scol];
      uint4 av0 = *(const uint4*)ap;
      uint4 av1 = *(const uint4*)(ap + 8);
      uint4 bv0, bv1;
      if (Wb_) {
        const u16* wp = &Wb_[(long)(n0 + srow) * K + k0 + scol];
        bv0 = *(const uint4*)wp;
        bv1 = *(const uint4*)(wp + 8);
      } else {
        const float* wp = &Wf_[(long)(n0 + srow) * K + k0 + scol];
        u16 tv[16];
#pragma unroll
        for (int qq = 0; qq < 16; ++qq) tv[qq] = f2bf(wp[qq]);
        bv0 = ((uint4*)tv)[0];
        bv1 = ((uint4*)tv)[1];
      }
      __syncthreads();
      *(uint4*)&As[srow][scol] = av0;
      *(uint4*)&As[srow][scol + 8] = av1;
      *(uint4*)&Bs[srow][scol] = bv0;
      *(uint4*)&Bs[srow][scol + 8] = bv1;
      __syncthreads();
      bf16x8 af[2][2], bfv[2][2];
#pragma unroll
      for (int kk = 0; kk < 2; ++kk) {
#pragma unroll
        for (int i = 0; i < 2; ++i)
          af[i][kk] = *(const bf16x8*)&As[wr * 32 + i * 16 + l16][kk * 32 + quad * 8];
#pragma unroll
        for (int j = 0; j < 2; ++j)
          bfv[j][kk] = *(const bf16x8*)&Bs[wc * 32 + j * 16 + l16][kk * 32 + quad * 8];
      }
#pragma unroll
      for (int kk = 0; kk < 2; ++kk)
#pragma unroll
        for (int i = 0; i < 2; ++i)
#pragma unroll
          for (int j = 0; j < 2; ++j)
            acc[i][j] = __builtin_amdgcn_mfma_f32_16x16x32_bf16(af[i][kk], bfv[j][kk], acc[i][j], 0, 0, 0);
    }
  }
#pragma unroll
  for (int j = 0; j < 2; ++j) {
    const int n = n0 + wc * 32 + j * 16 + l16;
    float bn = bias ? bias[n] : 0.0f;
    float srn[8];
    if (symS) {
      bn += sbr[n];
#pragma unroll
      for (int qq = 0; qq < 8; ++qq) srn[qq] = Srw[n * 8 + qq];
    }
#pragma unroll
    for (int i = 0; i < 2; ++i) {
#pragma unroll
      for (int r = 0; r < 4; ++r) {
        const int m = m0 + wr * 32 + i * 16 + quad * 4 + r;
        float v = acc[i][j][r] + bn;
        if (symS) {
#pragma unroll
          for (int qq = 0; qq < 8; ++qq) v += symS[(long)m * 128 + qq] * srn[qq];
        }
        if (doTanh) v = fast_tanh(v);
        if (outMode == 0) Cb[(long)m * N + n] = f2bf(v);
        else Cf[(long)m * N + n] = v;
      }
    }
  }
}

extern "C" void kernel_launch(void* const* d_in, const int* in_sizes, int n_in,
                              void* d_out, int out_size, void* d_ws, size_t ws_size,
                              hipStream_t stream) {
  const float* inp = (const float*)d_in[0];
  const float* sym = (const float*)d_in[1];
  const float* Wb  = (const float*)d_in[3];
  const float* bb  = (const float*)d_in[4];
  const float* Wl  = (const float*)d_in[5];
  const float* bl  = (const float*)d_in[6];
  const float* Wr  = (const float*)d_in[7];
  const float* Ws  = (const float*)d_in[8];
  const float* bs  = (const float*)d_in[9];
  const float* Sl  = (const float*)d_in[10];
  const float* sbl = (const float*)d_in[11];
  const float* Sr  = (const float*)d_in[12];
  const float* sbr = (const float*)d_in[13];
  const float* Ss  = (const float*)d_in[14];
  const float* sbs = (const float*)d_in[15];

  const long B = 2048, NB = 64, F = 512, H = 1024;
  const long WE = 524288;
  u16* ws = (u16*)d_ws;
  dim3 blk(256);

  // fused path: 5 bf16 weights + boxesT + fence (~139.5 MB, same as before)
  const size_t baseU16 = (size_t)5 * WE + (size_t)64 * B * F;
  const size_t needNew = baseU16 * 2 + 1024;

  if (ws_size >= needNew) {
    u16* WlB = ws;
    u16* WrB = WlB + WE;
    u16* WsB = WrB + WE;
    u16* SlB = WsB + WE;
    u16* SsB = SlB + WE;
    u16* boxesT = SsB + WE;                        // [64][2048][512]
    u16* accG = boxesT + (size_t)63 * 2048 * 512;  // overlay: boxesT[63] dead after t=0
    u16* hG = (u16*)d_out;                         // 4 MB scratch until final out
    u32* fence = (u32*)(ws + baseU16);             // 160 slots

    (void)hipMemsetAsync(fence, 0, 160 * sizeof(u32), stream);
    cvt_bf16<<<WE / 2048, blk, 0, stream>>>(Wl, WlB, (int)WE);
    cvt_bf16<<<WE / 2048, blk, 0, stream>>>(Wr, WrB, (int)WE);
    cvt_bf16<<<WE / 2048, blk, 0, stream>>>(Ws, WsB, (int)WE);
    cvt_bf16<<<WE / 2048, blk, 0, stream>>>(Sl, SlB, (int)WE);
    cvt_bf16<<<WE / 2048, blk, 0, stream>>>(Ss, SsB, (int)WE);
    box_allT<<<B, blk, 0, stream>>>(inp, Wb, bb, boxesT);
    chain2<<<dim3(256), dim3(512), 0, stream>>>(boxesT, WlB, WrB, WsB, SlB, SsB,
                                                bl, bs, sbl, sbr, sbs, Sr, sym,
                                                accG, hG, (float*)d_out, fence);
  } else {
    // fallback: bf16 weights if they fit, else fp32 staging
    dim3 gH(16, 32), gP(8, 32);
    const size_t szW = 5 * WE * 2, szBoxes = (size_t)B * NB * F * 2;
    const size_t szH = (size_t)B * H * 2, szAcc = (size_t)B * F * 2;
    const size_t needT2 = szW + szBoxes + szH + szAcc;
    const size_t needT3 = szBoxes + szH + szAcc;
    int tier = (ws_size >= needT2) ? 2 : (ws_size >= needT3) ? 3 : 4;
    u16 *WlB = nullptr, *WrB = nullptr, *WsB = nullptr, *SlB = nullptr, *SsB = nullptr;
    const float *WlF = Wl, *WrF = Wr, *WsF = Ws, *SlF = Sl, *SsF = Ss;
    u16* p = ws;
    if (tier == 2) {
      WlB = p; WrB = p + WE; WsB = p + 2 * WE; SlB = p + 3 * WE; SsB = p + 4 * WE;
      p += 5 * WE;
      cvt_bf16<<<WE / 2048, blk, 0, stream>>>(Wl, WlB, (int)WE);
      cvt_bf16<<<WE / 2048, blk, 0, stream>>>(Wr, WrB, (int)WE);
      cvt_bf16<<<WE / 2048, blk, 0, stream>>>(Ws, WsB, (int)WE);
      cvt_bf16<<<WE / 2048, blk, 0, stream>>>(Sl, SlB, (int)WE);
      cvt_bf16<<<WE / 2048, blk, 0, stream>>>(Ss, SsB, (int)WE);
      WlF = WrF = WsF = SlF = SsF = nullptr;
    }
    u16* boxes = p;
    p += B * NB * F;
    u16* hBuf = p; p += B * H;
    u16* accBuf = p;
    box_all_v2<<<B, blk, 0, stream>>>(inp, Wb, bb, boxes);
    const u16* curA = boxes + 63 * 512;
    int curLda = (int)(NB * F);
    for (int bp = 62; bp >= 0; --bp) {
      gemm64<<<gH, blk, 0, stream>>>(curA, curLda, WlB, WlF, 512,
                                     boxes + (long)bp * 512, (int)(NB * F), WrB, WrF, 512,
                                     bl, nullptr, nullptr, nullptr, 1, 0, hBuf, nullptr, 1024);
      gemm64<<<gP, blk, 0, stream>>>(hBuf, 1024, WsB, WsF, 1024,
                                     nullptr, 0, nullptr, nullptr, 0,
                                     bs, nullptr, nullptr, nullptr, 1, 0, accBuf, nullptr, 512);
      curA = accBuf; curLda = 512;
    }
    for (int symp = 15; symp >= 0; --symp) {
      gemm64<<<gH, blk, 0, stream>>>(accBuf, 512, SlB, SlF, 512,
                                     nullptr, 0, nullptr, nullptr, 0,
                                     sbl, sym + symp * 8, Sr, sbr, 1, 0, hBuf, nullptr, 1024);
      int om = (symp == 0) ? 1 : 0;
      gemm64<<<gP, blk, 0, stream>>>(hBuf, 1024, SsB, SsF, 1024,
                                     nullptr, 0, nullptr, nullptr, 0,
                                     sbs, nullptr, nullptr, nullptr, 1, om, accBuf, (float*)d_out, 512);
    }
  }
  (void)in_sizes; (void)n_in; (void)out_size;
}

// Round 7
// 3626.678 us; speedup vs baseline: 4.4552x; 1.0497x over previous
//
#include <hip/hip_runtime.h>
#include <cmath>

using u16 = unsigned short;
using u32 = unsigned int;
using u64 = unsigned long long;
using bf16x8 = __attribute__((ext_vector_type(8))) __bf16;
using f32x4 = __attribute__((ext_vector_type(4))) float;
using u32x4 = __attribute__((ext_vector_type(4))) u32;
using u32x2 = __attribute__((ext_vector_type(2))) u32;

__device__ __forceinline__ u16 f2bf(float f) {
  union { float f; u32 i; } x; x.f = f;
  u32 r = x.i + 0x7FFFu + ((x.i >> 16) & 1u);
  return (u16)(r >> 16);
}
__device__ __forceinline__ float fast_tanh(float x) {
  float e = __expf(2.0f * x);
  return 1.0f - 2.0f / (e + 1.0f);
}
__device__ __forceinline__ void load_lds16(const u16* g, u16* l) {
  __builtin_amdgcn_global_load_lds((const __attribute__((address_space(1))) u32*)g,
                                   (__attribute__((address_space(3))) u32*)l, 16, 0, 0);
}
// operand-tile byte offset with XOR swizzle (row stride 1024B, bits 4-6 xor'd)
__device__ __forceinline__ int sxo(int row, int kb) {
  return row * 1024 + (kb ^ ((row & 7) << 4));
}

// ---------------- fp32 -> bf16 bulk convert ----------------
__global__ void cvt_bf16(const float* __restrict__ src, u16* __restrict__ dst, int n) {
  int i = (blockIdx.x * 256 + threadIdx.x) * 8;
  if (i + 8 <= n) {
    float4 a = *(const float4*)(src + i), b = *(const float4*)(src + i + 4);
    u16 t[8] = {f2bf(a.x), f2bf(a.y), f2bf(a.z), f2bf(a.w),
                f2bf(b.x), f2bf(b.y), f2bf(b.z), f2bf(b.w)};
    *(uint4*)(dst + i) = *(uint4*)t;
  }
}

// ---------------- boxesT[i][b][f] = tanh(inp[b][i]@Wb^T + bb) ----------------
__global__ __launch_bounds__(256) void box_allT(const float* __restrict__ inp,
    const float* __restrict__ Wb, const float* __restrict__ bb, u16* __restrict__ boxesT) {
  int b = blockIdx.x, t = threadIdx.x;
  __shared__ float sin_[64][12];
  for (int idx = t; idx < 768; idx += 256) sin_[idx / 12][idx % 12] = inp[(long)b * 768 + idx];
  int f0 = (t & 127) * 4, hf = t >> 7;
  float w[4][12], bz[4];
#pragma unroll
  for (int r = 0; r < 4; ++r) {
    bz[r] = bb[f0 + r];
#pragma unroll
    for (int q = 0; q < 12; ++q) w[r][q] = Wb[(f0 + r) * 12 + q];
  }
  __syncthreads();
  for (int i = hf; i < 64; i += 2) {
    float a[4] = {bz[0], bz[1], bz[2], bz[3]};
#pragma unroll
    for (int q = 0; q < 12; ++q) {
      float x = sin_[i][q];
#pragma unroll
      for (int r = 0; r < 4; ++r) a[r] += x * w[r][q];
    }
    u16 p[4];
#pragma unroll
    for (int r = 0; r < 4; ++r) p[r] = f2bf(fast_tanh(a[r]));
    __builtin_nontemporal_store(*(u32x2*)p, (u32x2*)&boxesT[((long)i * 2048 + b) * 512 + f0]);
  }
}

// ======== chain2: N-split cooperative chain, XCD-resident weight slices ========
// 256 blocks: c = bid&7 (col-slice == XCD -> per-XCD weights 384KB, L2-resident
// across all steps), r = bid>>3 (row-group, 64 rows). Per step:
//   H: h[64 x 128c] = tanh(acc@Wl_c^T + box@Wr_c^T + bl)   (sym: Sl_c + sym@Sr^T)
//   group fence(8); P: acc[64 x 64c] = tanh(h@Ws_c^T + bs); group fence(8).
// h/acc exchanged via relaxed AGENT atomics (IC-coherent). Fences are per-row-
// group (8 blocks), not global. Weight chunks: depth-3 global_load_lds pipeline,
// raw s_barrier + counted vmcnt. Operand tiles XOR-swizzled.
__global__ __launch_bounds__(512, 1) void chain2(
    const u16* __restrict__ boxesT,
    const u16* __restrict__ Wl, const u16* __restrict__ Wr, const u16* __restrict__ Ws,
    const u16* __restrict__ Sl, const u16* __restrict__ Ss,
    const float* __restrict__ bl, const float* __restrict__ bs,
    const float* __restrict__ sbl, const float* __restrict__ sbr,
    const float* __restrict__ sbs, const float* __restrict__ SrF,
    const float* __restrict__ sym,
    u16* __restrict__ accG, u16* __restrict__ hG, float* __restrict__ outF,
    u32* __restrict__ fence) {
  __shared__ u16 sX0[64 * 512];   // acc (H) / h lo-half (P); epilogue: pack+sym overlay
  __shared__ u16 sX1[64 * 512];   // box (H) / h hi-half (P)
  __shared__ u16 sW[3 * 4096];    // 3 x 8KB weight chunk bufs

  const int tid = threadIdx.x, lane = tid & 63, w = tid >> 6;
  const int qq = lane >> 4, l16 = lane & 15;
  const int wr2 = w >> 1, wc2 = w & 1;
  const int bid = blockIdx.x;
  const int c = bid & 7, r = bid >> 3;  // bid%8 = c -> col-slice pinned to one XCD
  const int m0 = r * 64;
  char* sX0b = (char*)sX0;
  char* sX1b = (char*)sX1;
  u64* hU = (u64*)hG;
  u64* aU = (u64*)accG;

  const int arow = wr2 * 16 + l16;
  const int aX = (arow & 7) << 4;

  // H-chunk gll source precompute: chunk layout [128 n][32 k], swizzle bits 4-5
  const int gn = tid >> 2;
  const int gkb = ((tid & 3) * 16) ^ (((gn >> 1) & 3) << 4);
  // P-chunk: layout [64 n][64 k], swizzle bits 4-6
  const int pr = tid >> 3;
  const int pkb = ((tid & 7) * 16) ^ ((pr & 7) << 4);

  int hb[4];
#pragma unroll
  for (int j = 0; j < 4; ++j) {
    int nl = wc2 * 64 + j * 16 + l16;
    hb[j] = nl * 64 + ((qq * 16) ^ (((nl >> 1) & 3) << 4));
  }
  int pb[2][2];
#pragma unroll
  for (int j = 0; j < 2; ++j)
#pragma unroll
    for (int s1 = 0; s1 < 2; ++s1) {
      int rl = wc2 * 32 + j * 16 + l16;
      pb[j][s1] = rl * 128 + ((s1 * 64 + qq * 16) ^ ((rl & 7) << 4));
    }

  for (int t = 0; t < 79; ++t) {
    const bool symPhase = (t >= 63);
    const bool last = (t == 78);
    // ================= H phase =================
    // stage acc -> sX0
    if (t == 0) {
      const u16* src = boxesT + ((long)63 * 2048 + m0) * 512;
#pragma unroll
      for (int i = 0; i < 8; ++i) {
        int idx = i * 512 + tid, row = idx >> 6, u = idx & 63;
        *(u32x4*)(sX0b + sxo(row, u * 16)) = *(const u32x4*)(src + (long)row * 512 + u * 8);
      }
    } else {
#pragma unroll
      for (int i = 0; i < 16; ++i) {
        int idx = i * 512 + tid, row = idx >> 7, u = idx & 127;
        u64 v = __hip_atomic_load(aU + (long)(m0 + row) * 128 + u,
                                  __ATOMIC_RELAXED, __HIP_MEMORY_SCOPE_AGENT);
        *(u64*)(sX0b + sxo(row, u * 8)) = v;
      }
    }
    if (!symPhase) {  // stage box -> sX1
      const u16* src = boxesT + ((long)(62 - t) * 2048 + m0) * 512;
#pragma unroll
      for (int i = 0; i < 8; ++i) {
        int idx = i * 512 + tid, row = idx >> 6, u = idx & 63;
        *(u32x4*)(sX1b + sxo(row, u * 16)) = *(const u32x4*)(src + (long)row * 512 + u * 8);
      }
    }
    __syncthreads();  // drains vmcnt -> clean baseline for counted pipeline

    const u16* WA = symPhase ? Sl : Wl;
    const int nch = symPhase ? 16 : 32;
    const long gWoff = ((long)(c * 128 + gn)) * 512 + (gkb >> 1);

    f32x4 C[4];
#pragma unroll
    for (int j = 0; j < 4; ++j) C[j] = (f32x4){0.f, 0.f, 0.f, 0.f};

    {
      // prologue: chunks 0,1 into bufs 0,1
      if (symPhase) {
        load_lds16(WA + gWoff,      sW + 0 * 4096 + tid * 8);
        load_lds16(WA + gWoff + 32, sW + 1 * 4096 + tid * 8);
      } else {
        load_lds16(WA + gWoff, sW + 0 * 4096 + tid * 8);
        load_lds16(Wr + gWoff, sW + 1 * 4096 + tid * 8);
      }
      int cb = 0, nb = 2;
      for (int ci = 0; ci < nch; ++ci) {
        if (ci + 2 < nch) {
          int cj = ci + 2;
          int u = symPhase ? cj : (cj >> 1);
          if (symPhase || !(cj & 1)) load_lds16(WA + gWoff + u * 32, sW + nb * 4096 + tid * 8);
          else                       load_lds16(Wr + gWoff + u * 32, sW + nb * 4096 + tid * 8);
        }
        if (ci + 2 < nch)      asm volatile("s_waitcnt vmcnt(2)" ::: "memory");
        else if (ci + 1 < nch) asm volatile("s_waitcnt vmcnt(1)" ::: "memory");
        else                   asm volatile("s_waitcnt vmcnt(0)" ::: "memory");
        __builtin_amdgcn_s_barrier();
        asm volatile("" ::: "memory");
        {
          const char* bufb = (const char*)sW + cb * 8192;
          int u = symPhase ? ci : (ci >> 1);
          const char* ab = (!symPhase && (ci & 1)) ? sX1b : sX0b;
          int akb = (u * 64 + qq * 16) ^ aX;
          bf16x8 af = *(const bf16x8*)(ab + arow * 1024 + akb);
#pragma unroll
          for (int j = 0; j < 4; ++j)
            C[j] = __builtin_amdgcn_mfma_f32_16x16x32_bf16(
                af, *(const bf16x8*)(bufb + hb[j]), C[j], 0, 0, 0);
        }
        __builtin_amdgcn_s_barrier();
        asm volatile("" ::: "memory");
        cb = (cb == 2) ? 0 : cb + 1;
        nb = (nb == 2) ? 0 : nb + 1;
      }
    }

    // hoisted P-weight prologue: latency hides under epilogue + fence
    const u16* WP = symPhase ? Ss : Ws;
    const long gPoff = ((long)(c * 64 + pr)) * 1024 + (pkb >> 1);
    load_lds16(WP + gPoff + 0 * 64, sW + 0 * 4096 + tid * 8);
    load_lds16(WP + gPoff + 1 * 64, sW + 1 * 4096 + tid * 8);

    // ---- H epilogue: tanh(+bias [+sym@Sr]) -> pack -> atomic store to hG ----
    if (symPhase) {
      float* sSymF = (float*)(sX0b + 20480);
      int symp = 78 - t;
      sSymF[tid] = sym[((long)(m0 + (tid >> 3)) * 16 + symp) * 8 + (tid & 7)];
      __syncthreads();
    }
    u16* sP = (u16*)sX0b;
#pragma unroll
    for (int j = 0; j < 4; ++j) {
      int lcol = wc2 * 64 + j * 16 + l16;
      int col = c * 128 + lcol;
      if (!symPhase) {
        float bn = bl[col];
#pragma unroll
        for (int rr = 0; rr < 4; ++rr) {
          int m = wr2 * 16 + qq * 4 + rr;
          sP[m * 136 + lcol] = f2bf(fast_tanh(C[j][rr] + bn));
        }
      } else {
        float bn = sbl[col] + sbr[col];
        float sr[8];
        *(float4*)&sr[0] = *(const float4*)&SrF[(long)col * 8];
        *(float4*)&sr[4] = *(const float4*)&SrF[(long)col * 8 + 4];
        const float* sSymF = (const float*)(sX0b + 20480);
#pragma unroll
        for (int rr = 0; rr < 4; ++rr) {
          int m = wr2 * 16 + qq * 4 + rr;
          float v = C[j][rr] + bn;
          const float* sv = sSymF + m * 8;
#pragma unroll
          for (int k = 0; k < 8; ++k) v += sv[k] * sr[k];
          sP[m * 136 + lcol] = f2bf(fast_tanh(v));
        }
      }
    }
    __syncthreads();
#pragma unroll
    for (int i = 0; i < 4; ++i) {
      int idx = i * 512 + tid, row = idx >> 5, cu = idx & 31;
      u64 v = *(const u64*)(sX0b + row * 272 + cu * 8);
      __hip_atomic_store(hU + (long)(m0 + row) * 256 + c * 32 + cu, v,
                         __ATOMIC_RELAXED, __HIP_MEMORY_SCOPE_AGENT);
    }
    // ---- group fence (8 blocks sharing r): all h for this row-group written ----
    __syncthreads();
    if (tid == 0) {
      u32* f = fence + (2 * t) * 32 + r;
      __hip_atomic_fetch_add(f, 1u, __ATOMIC_RELAXED, __HIP_MEMORY_SCOPE_AGENT);
      while (__hip_atomic_load(f, __ATOMIC_RELAXED, __HIP_MEMORY_SCOPE_AGENT) < 8u)
        __builtin_amdgcn_s_sleep(2);
    }
    __syncthreads();
    asm volatile("" ::: "memory");

    // ================= P phase =================
    // stage h -> sX0 (k<512) / sX1 (k>=512)
    {
      const int u = tid & 255;
      const bool lo = (u < 128);
#pragma unroll
      for (int i = 0; i < 32; ++i) {
        int idx = i * 512 + tid, row = idx >> 8;
        u64 v = __hip_atomic_load(hU + (long)(m0 + row) * 256 + u,
                                  __ATOMIC_RELAXED, __HIP_MEMORY_SCOPE_AGENT);
        if (lo) *(u64*)(sX0b + sxo(row, u * 8)) = v;
        else    *(u64*)(sX1b + sxo(row, (u - 128) * 8)) = v;
      }
    }
    __syncthreads();
    if (last) {  // out writes will alias hG: wait until ALL blocks staged h
      if (tid == 0) {
        u32* f = fence + 5056;
        __hip_atomic_fetch_add(f, 1u, __ATOMIC_RELAXED, __HIP_MEMORY_SCOPE_AGENT);
        while (__hip_atomic_load(f, __ATOMIC_RELAXED, __HIP_MEMORY_SCOPE_AGENT) < 256u)
          __builtin_amdgcn_s_sleep(2);
      }
      __syncthreads();
      asm volatile("" ::: "memory");
    }

    f32x4 D[2];
    D[0] = (f32x4){0.f, 0.f, 0.f, 0.f};
    D[1] = (f32x4){0.f, 0.f, 0.f, 0.f};
    {
      // prologue chunks already in flight (hoisted above)
      int cb = 0, nb = 2;
      for (int ci = 0; ci < 16; ++ci) {
        if (ci + 2 < 16) load_lds16(WP + gPoff + (ci + 2) * 64, sW + nb * 4096 + tid * 8);
        if (ci + 2 < 16)      asm volatile("s_waitcnt vmcnt(2)" ::: "memory");
        else if (ci + 1 < 16) asm volatile("s_waitcnt vmcnt(1)" ::: "memory");
        else                  asm volatile("s_waitcnt vmcnt(0)" ::: "memory");
        __builtin_amdgcn_s_barrier();
        asm volatile("" ::: "memory");
        {
          const char* bufb = (const char*)sW + cb * 8192;
          const char* ab = (ci < 8) ? sX0b : sX1b;
          int base = (ci & 7) * 128;
#pragma unroll
          for (int s1 = 0; s1 < 2; ++s1) {
            int akb = (base + s1 * 64 + qq * 16) ^ aX;
            bf16x8 af = *(const bf16x8*)(ab + arow * 1024 + akb);
#pragma unroll
            for (int j = 0; j < 2; ++j)
              D[j] = __builtin_amdgcn_mfma_f32_16x16x32_bf16(
                  af, *(const bf16x8*)(bufb + pb[j][s1]), D[j], 0, 0, 0);
          }
        }
        __builtin_amdgcn_s_barrier();
        asm volatile("" ::: "memory");
        cb = (cb == 2) ? 0 : cb + 1;
        nb = (nb == 2) ? 0 : nb + 1;
      }
    }

    // ---- P epilogue ----
    const float* b2 = symPhase ? sbs : bs;
    if (!last) {
#pragma unroll
      for (int j = 0; j < 2; ++j) {
        int lcol = wc2 * 32 + j * 16 + l16;
        float bn = b2[c * 64 + lcol];
#pragma unroll
        for (int rr = 0; rr < 4; ++rr) {
          int m = wr2 * 16 + qq * 4 + rr;
          sP[m * 72 + lcol] = f2bf(fast_tanh(D[j][rr] + bn));
        }
      }
      __syncthreads();
#pragma unroll
      for (int i = 0; i < 2; ++i) {
        int idx = i * 512 + tid, row = idx >> 4, cu = idx & 15;
        u64 v = *(const u64*)(sX0b + row * 144 + cu * 8);
        __hip_atomic_store(aU + (long)(m0 + row) * 128 + c * 16 + cu, v,
                           __ATOMIC_RELAXED, __HIP_MEMORY_SCOPE_AGENT);
      }
      // ---- group fence: all acc for this row-group written ----
      __syncthreads();
      if (tid == 0) {
        u32* f = fence + (2 * t + 1) * 32 + r;
        __hip_atomic_fetch_add(f, 1u, __ATOMIC_RELAXED, __HIP_MEMORY_SCOPE_AGENT);
        while (__hip_atomic_load(f, __ATOMIC_RELAXED, __HIP_MEMORY_SCOPE_AGENT) < 8u)
          __builtin_amdgcn_s_sleep(2);
      }
      __syncthreads();
      asm volatile("" ::: "memory");
    } else {
#pragma unroll
      for (int j = 0; j < 2; ++j) {
        int lcol = wc2 * 32 + j * 16 + l16;
        int col = c * 64 + lcol;
        float bn = b2[col];
#pragma unroll
        for (int rr = 0; rr < 4; ++rr) {
          int m = wr2 * 16 + qq * 4 + rr;
          outF[(long)(m0 + m) * 512 + col] = fast_tanh(D[j][rr] + bn);
        }
      }
    }
  }
}

// ================= fallback kernels (small-ws path) =================
__global__ __launch_bounds__(256) void box_all_v2(const float* __restrict__ inp,
    const float* __restrict__ Wb, const float* __restrict__ bb, u16* __restrict__ boxes) {
  int b = blockIdx.x, t = threadIdx.x;
  __shared__ float sin_[64][12];
  for (int idx = t; idx < 768; idx += 256) sin_[idx / 12][idx % 12] = inp[(long)b * 768 + idx];
  const int f0 = t * 2;
  float w0[12], w1[12];
#pragma unroll
  for (int q = 0; q < 12; ++q) { w0[q] = Wb[f0 * 12 + q]; w1[q] = Wb[(f0 + 1) * 12 + q]; }
  float b0 = bb[f0], b1 = bb[f0 + 1];
  __syncthreads();
  for (int i = 0; i < 64; ++i) {
    float a0 = b0, a1 = b1;
#pragma unroll
    for (int q = 0; q < 12; ++q) { float x = sin_[i][q]; a0 += x * w0[q]; a1 += x * w1[q]; }
    u32 pk = (u32)f2bf(fast_tanh(a0)) | ((u32)f2bf(fast_tanh(a1)) << 16);
    *(u32*)&boxes[(((long)b * 64 + i) * 512) + f0] = pk;
  }
}

__global__ __launch_bounds__(256) void gemm64(
    const u16* __restrict__ A1, int lda1,
    const u16* __restrict__ W1b, const float* __restrict__ W1f, int K1,
    const u16* __restrict__ A2, int lda2,
    const u16* __restrict__ W2b, const float* __restrict__ W2f, int K2,
    const float* __restrict__ bias,
    const float* __restrict__ symS, const float* __restrict__ Srw, const float* __restrict__ sbr,
    int doTanh, int outMode,
    u16* __restrict__ Cb, float* __restrict__ Cf, int N) {
  __shared__ u16 As[64][72];
  __shared__ u16 Bs[64][72];
  const int tid = threadIdx.x;
  const int lane = tid & 63, w = tid >> 6;
  const int wr = w >> 1, wc = w & 1;
  const int quad = lane >> 4, l16 = lane & 15;
  const int m0 = blockIdx.y * 64, n0 = blockIdx.x * 64;
  const int srow = tid >> 2, scol = (tid & 3) * 16;
  f32x4 acc[2][2];
#pragma unroll
  for (int i = 0; i < 2; ++i)
#pragma unroll
    for (int j = 0; j < 2; ++j) acc[i][j] = (f32x4){0.f, 0.f, 0.f, 0.f};
#pragma unroll
  for (int pair = 0; pair < 2; ++pair) {
    const u16* A = pair ? A2 : A1;
    const u16* Wb_ = pair ? W2b : W1b;
    const float* Wf_ = pair ? W2f : W1f;
    const int lda = pair ? lda2 : lda1;
    const int K = pair ? K2 : K1;
    if (K == 0) continue;
    for (int k0 = 0; k0 < K; k0 += 64) {
      const u16* ap = &A[(long)(m0 + srow) * lda + k0 + scol];
      uint4 av0 = *(const uint4*)ap;
      uint4 av1 = *(const uint4*)(ap + 8);
      uint4 bv0, bv1;
      if (Wb_) {
        const u16* wp = &Wb_[(long)(n0 + srow) * K + k0 + scol];
        bv0 = *(const uint4*)wp;
        bv1 = *(const uint4*)(wp + 8);
      } else {
        const float* wp = &Wf_[(long)(n0 + srow) * K + k0 + scol];
        u16 tv[16];
#pragma unroll
        for (int qq = 0; qq < 16; ++qq) tv[qq] = f2bf(wp[qq]);
        bv0 = ((uint4*)tv)[0];
        bv1 = ((uint4*)tv)[1];
      }
      __syncthreads();
      *(uint4*)&As[srow][scol] = av0;
      *(uint4*)&As[srow][scol + 8] = av1;
      *(uint4*)&Bs[srow][scol] = bv0;
      *(uint4*)&Bs[srow][scol + 8] = bv1;
      __syncthreads();
      bf16x8 af[2][2], bfv[2][2];
#pragma unroll
      for (int kk = 0; kk < 2; ++kk) {
#pragma unroll
        for (int i = 0; i < 2; ++i)
          af[i][kk] = *(const bf16x8*)&As[wr * 32 + i * 16 + l16][kk * 32 + quad * 8];
#pragma unroll
        for (int j = 0; j < 2; ++j)
          bfv[j][kk] = *(const bf16x8*)&Bs[wc * 32 + j * 16 + l16][kk * 32 + quad * 8];
      }
#pragma unroll
      for (int kk = 0; kk < 2; ++kk)
#pragma unroll
        for (int i = 0; i < 2; ++i)
#pragma unroll
          for (int j = 0; j < 2; ++j)
            acc[i][j] = __builtin_amdgcn_mfma_f32_16x16x32_bf16(af[i][kk], bfv[j][kk], acc[i][j], 0, 0, 0);
    }
  }
#pragma unroll
  for (int j = 0; j < 2; ++j) {
    const int n = n0 + wc * 32 + j * 16 + l16;
    float bn = bias ? bias[n] : 0.0f;
    float srn[8];
    if (symS) {
      bn += sbr[n];
#pragma unroll
      for (int qq = 0; qq < 8; ++qq) srn[qq] = Srw[n * 8 + qq];
    }
#pragma unroll
    for (int i = 0; i < 2; ++i) {
#pragma unroll
      for (int r = 0; r < 4; ++r) {
        const int m = m0 + wr * 32 + i * 16 + quad * 4 + r;
        float v = acc[i][j][r] + bn;
        if (symS) {
#pragma unroll
          for (int qq = 0; qq < 8; ++qq) v += symS[(long)m * 128 + qq] * srn[qq];
        }
        if (doTanh) v = fast_tanh(v);
        if (outMode == 0) Cb[(long)m * N + n] = f2bf(v);
        else Cf[(long)m * N + n] = v;
      }
    }
  }
}

extern "C" void kernel_launch(void* const* d_in, const int* in_sizes, int n_in,
                              void* d_out, int out_size, void* d_ws, size_t ws_size,
                              hipStream_t stream) {
  const float* inp = (const float*)d_in[0];
  const float* sym = (const float*)d_in[1];
  const float* Wb  = (const float*)d_in[3];
  const float* bb  = (const float*)d_in[4];
  const float* Wl  = (const float*)d_in[5];
  const float* bl  = (const float*)d_in[6];
  const float* Wr  = (const float*)d_in[7];
  const float* Ws  = (const float*)d_in[8];
  const float* bs  = (const float*)d_in[9];
  const float* Sl  = (const float*)d_in[10];
  const float* sbl = (const float*)d_in[11];
  const float* Sr  = (const float*)d_in[12];
  const float* sbr = (const float*)d_in[13];
  const float* Ss  = (const float*)d_in[14];
  const float* sbs = (const float*)d_in[15];

  const long B = 2048, NB = 64, F = 512, H = 1024;
  const long WE = 524288;
  u16* ws = (u16*)d_ws;
  dim3 blk(256);

  // fused path: 5 bf16 weights + boxesT + fence (~139.5 MB)
  const size_t baseU16 = (size_t)5 * WE + (size_t)64 * B * F;
  const size_t needNew = baseU16 * 2 + 20480;

  if (ws_size >= needNew) {
    u16* WlB = ws;
    u16* WrB = WlB + WE;
    u16* WsB = WrB + WE;
    u16* SlB = WsB + WE;
    u16* SsB = SlB + WE;
    u16* boxesT = SsB + WE;                        // [64][2048][512]
    u16* accG = boxesT + (size_t)63 * 2048 * 512;  // overlay: boxesT[63] dead after t=0
    u16* hG = (u16*)d_out;                         // 4 MB scratch until final out
    u32* fence = (u32*)(ws + baseU16);             // 79*2*32 group slots + global slot

    (void)hipMemsetAsync(fence, 0, 20480, stream);
    cvt_bf16<<<WE / 2048, blk, 0, stream>>>(Wl, WlB, (int)WE);
    cvt_bf16<<<WE / 2048, blk, 0, stream>>>(Wr, WrB, (int)WE);
    cvt_bf16<<<WE / 2048, blk, 0, stream>>>(Ws, WsB, (int)WE);
    cvt_bf16<<<WE / 2048, blk, 0, stream>>>(Sl, SlB, (int)WE);
    cvt_bf16<<<WE / 2048, blk, 0, stream>>>(Ss, SsB, (int)WE);
    box_allT<<<B, blk, 0, stream>>>(inp, Wb, bb, boxesT);
    chain2<<<dim3(256), dim3(512), 0, stream>>>(boxesT, WlB, WrB, WsB, SlB, SsB,
                                                bl, bs, sbl, sbr, sbs, Sr, sym,
                                                accG, hG, (float*)d_out, fence);
  } else {
    // fallback: bf16 weights if they fit, else fp32 staging
    dim3 gH(16, 32), gP(8, 32);
    const size_t szW = 5 * WE * 2, szBoxes = (size_t)B * NB * F * 2;
    const size_t szH = (size_t)B * H * 2, szAcc = (size_t)B * F * 2;
    const size_t needT2 = szW + szBoxes + szH + szAcc;
    const size_t needT3 = szBoxes + szH + szAcc;
    int tier = (ws_size >= needT2) ? 2 : (ws_size >= needT3) ? 3 : 4;
    u16 *WlB = nullptr, *WrB = nullptr, *WsB = nullptr, *SlB = nullptr, *SsB = nullptr;
    const float *WlF = Wl, *WrF = Wr, *WsF = Ws, *SlF = Sl, *SsF = Ss;
    u16* p = ws;
    if (tier == 2) {
      WlB = p; WrB = p + WE; WsB = p + 2 * WE; SlB = p + 3 * WE; SsB = p + 4 * WE;
      p += 5 * WE;
      cvt_bf16<<<WE / 2048, blk, 0, stream>>>(Wl, WlB, (int)WE);
      cvt_bf16<<<WE / 2048, blk, 0, stream>>>(Wr, WrB, (int)WE);
      cvt_bf16<<<WE / 2048, blk, 0, stream>>>(Ws, WsB, (int)WE);
      cvt_bf16<<<WE / 2048, blk, 0, stream>>>(Sl, SlB, (int)WE);
      cvt_bf16<<<WE / 2048, blk, 0, stream>>>(Ss, SsB, (int)WE);
      WlF = WrF = WsF = SlF = SsF = nullptr;
    }
    u16* boxes = p;
    p += B * NB * F;
    u16* hBuf = p; p += B * H;
    u16* accBuf = p;
    box_all_v2<<<B, blk, 0, stream>>>(inp, Wb, bb, boxes);
    const u16* curA = boxes + 63 * 512;
    int curLda = (int)(NB * F);
    for (int bp = 62; bp >= 0; --bp) {
      gemm64<<<gH, blk, 0, stream>>>(curA, curLda, WlB, WlF, 512,
                                     boxes + (long)bp * 512, (int)(NB * F), WrB, WrF, 512,
                                     bl, nullptr, nullptr, nullptr, 1, 0, hBuf, nullptr, 1024);
      gemm64<<<gP, blk, 0, stream>>>(hBuf, 1024, WsB, WsF, 1024,
                                     nullptr, 0, nullptr, nullptr, 0,
                                     bs, nullptr, nullptr, nullptr, 1, 0, accBuf, nullptr, 512);
      curA = accBuf; curLda = 512;
    }
    for (int symp = 15; symp >= 0; --symp) {
      gemm64<<<gH, blk, 0, stream>>>(accBuf, 512, SlB, SlF, 512,
                                     nullptr, 0, nullptr, nullptr, 0,
                                     sbl, sym + symp * 8, Sr, sbr, 1, 0, hBuf, nullptr, 1024);
      int om = (symp == 0) ? 1 : 0;
      gemm64<<<gP, blk, 0, stream>>>(hBuf, 1024, SsB, SsF, 1024,
                                     nullptr, 0, nullptr, nullptr, 0,
                                     sbs, nullptr, nullptr, nullptr, 1, om, accBuf, (float*)d_out, 512);
    }
  }
  (void)in_sizes; (void)n_in; (void)out_size;
}

// Round 8
// 2621.881 us; speedup vs baseline: 6.1626x; 1.3832x over previous
//
#include <hip/hip_runtime.h>
#include <cmath>

using u16 = unsigned short;
using u32 = unsigned int;
using u64 = unsigned long long;
using bf16x8 = __attribute__((ext_vector_type(8))) __bf16;
using f32x4 = __attribute__((ext_vector_type(4))) float;
using u32x4 = __attribute__((ext_vector_type(4))) u32;
using u32x2 = __attribute__((ext_vector_type(2))) u32;

__device__ __forceinline__ u16 f2bf(float f) {
  union { float f; u32 i; } x; x.f = f;
  u32 r = x.i + 0x7FFFu + ((x.i >> 16) & 1u);
  return (u16)(r >> 16);
}
__device__ __forceinline__ float fast_tanh(float x) {
  float e = __expf(2.0f * x);
  return 1.0f - 2.0f / (e + 1.0f);
}
__device__ __forceinline__ void load_lds16(const u16* g, u16* l) {
  __builtin_amdgcn_global_load_lds((const __attribute__((address_space(1))) u32*)g,
                                   (__attribute__((address_space(3))) u32*)l, 16, 0, 0);
}
// agent-coherent 16B load/store (same sc1 path as agent atomics, 2x wider)
__device__ __forceinline__ u32x4 ld16_sys(const void* p) {
  u32x4 r;
  asm volatile("global_load_dwordx4 %0, %1, off sc1" : "=v"(r) : "v"(p));
  return r;
}
__device__ __forceinline__ void st16_sys(void* p, u32x4 v) {
  asm volatile("global_store_dwordx4 %0, %1, off sc1" :: "v"(p), "v"(v) : "memory");
}
// operand-tile byte offset with XOR swizzle (row stride 1024B, bits 4-6 xor'd)
__device__ __forceinline__ int sxo(int row, int kb) {
  return row * 1024 + (kb ^ ((row & 7) << 4));
}

// ---------------- fp32 -> bf16 bulk convert ----------------
__global__ void cvt_bf16(const float* __restrict__ src, u16* __restrict__ dst, int n) {
  int i = (blockIdx.x * 256 + threadIdx.x) * 8;
  if (i + 8 <= n) {
    float4 a = *(const float4*)(src + i), b = *(const float4*)(src + i + 4);
    u16 t[8] = {f2bf(a.x), f2bf(a.y), f2bf(a.z), f2bf(a.w),
                f2bf(b.x), f2bf(b.y), f2bf(b.z), f2bf(b.w)};
    *(uint4*)(dst + i) = *(uint4*)t;
  }
}

// ---------------- boxesT[i][b][f] = tanh(inp[b][i]@Wb^T + bb) ----------------
__global__ __launch_bounds__(256) void box_allT(const float* __restrict__ inp,
    const float* __restrict__ Wb, const float* __restrict__ bb, u16* __restrict__ boxesT) {
  int b = blockIdx.x, t = threadIdx.x;
  __shared__ float sin_[64][12];
  for (int idx = t; idx < 768; idx += 256) sin_[idx / 12][idx % 12] = inp[(long)b * 768 + idx];
  int f0 = (t & 127) * 4, hf = t >> 7;
  float w[4][12], bz[4];
#pragma unroll
  for (int r = 0; r < 4; ++r) {
    bz[r] = bb[f0 + r];
#pragma unroll
    for (int q = 0; q < 12; ++q) w[r][q] = Wb[(f0 + r) * 12 + q];
  }
  __syncthreads();
  for (int i = hf; i < 64; i += 2) {
    float a[4] = {bz[0], bz[1], bz[2], bz[3]};
#pragma unroll
    for (int q = 0; q < 12; ++q) {
      float x = sin_[i][q];
#pragma unroll
      for (int r = 0; r < 4; ++r) a[r] += x * w[r][q];
    }
    u16 p[4];
#pragma unroll
    for (int r = 0; r < 4; ++r) p[r] = f2bf(fast_tanh(a[r]));
    __builtin_nontemporal_store(*(u32x2*)p, (u32x2*)&boxesT[((long)i * 2048 + b) * 512 + f0]);
  }
}

// ======== chain2: N-split cooperative chain, XCD-resident weight slices ========
// 256 blocks: c = bid&7 (col-slice == XCD), r = bid>>3 (row-group, 64 rows).
// h/acc exchanged via 16B sc1 (agent-coherent) loads/stores, batched 8-deep.
// Weight chunks: 3-buf single-barrier gll pipeline with counted vmcnt.
__global__ __launch_bounds__(512, 1) void chain2(
    const u16* __restrict__ boxesT,
    const u16* __restrict__ Wl, const u16* __restrict__ Wr, const u16* __restrict__ Ws,
    const u16* __restrict__ Sl, const u16* __restrict__ Ss,
    const float* __restrict__ bl, const float* __restrict__ bs,
    const float* __restrict__ sbl, const float* __restrict__ sbr,
    const float* __restrict__ sbs, const float* __restrict__ SrF,
    const float* __restrict__ sym,
    u16* __restrict__ accG, u16* __restrict__ hG, float* __restrict__ outF,
    u32* __restrict__ fence) {
  __shared__ u16 sX0[64 * 512];   // acc (H) / h lo-half (P); epilogue: pack+sym overlay
  __shared__ u16 sX1[64 * 512];   // box (H) / h hi-half (P)
  __shared__ u16 sW[3 * 4096];    // 3 x 8KB weight chunk bufs

  const int tid = threadIdx.x, lane = tid & 63, w = tid >> 6;
  const int qq = lane >> 4, l16 = lane & 15;
  const int wr2 = w >> 1, wc2 = w & 1;
  const int bid = blockIdx.x;
  const int c = bid & 7, r = bid >> 3;
  const int m0 = r * 64;
  char* sX0b = (char*)sX0;
  char* sX1b = (char*)sX1;
  char* hB = (char*)hG + (long)m0 * 2048;    // h row stride 2048B
  char* aB = (char*)accG + (long)m0 * 1024;  // acc row stride 1024B

  const int arow = wr2 * 16 + l16;
  const int aX = (arow & 7) << 4;

  // H-chunk gll source: chunk layout [128 n][32 k], swizzle bits 4-5
  const int gn = tid >> 2;
  const int gkb = ((tid & 3) * 16) ^ (((gn >> 1) & 3) << 4);
  // P-chunk: layout [64 n][64 k], swizzle bits 4-6
  const int pr = tid >> 3;
  const int pkb = ((tid & 7) * 16) ^ ((pr & 7) << 4);

  int hb[4];
#pragma unroll
  for (int j = 0; j < 4; ++j) {
    int nl = wc2 * 64 + j * 16 + l16;
    hb[j] = nl * 64 + ((qq * 16) ^ (((nl >> 1) & 3) << 4));
  }
  int pb[2][2];
#pragma unroll
  for (int j = 0; j < 2; ++j)
#pragma unroll
    for (int s1 = 0; s1 < 2; ++s1) {
      int rl = wc2 * 32 + j * 16 + l16;
      pb[j][s1] = rl * 128 + ((s1 * 64 + qq * 16) ^ ((rl & 7) << 4));
    }

  for (int t = 0; t < 79; ++t) {
    const bool symPhase = (t >= 63);
    const bool last = (t == 78);
    // ================= H phase: stage acc + box =================
    if (t == 0) {
      const u16* src = boxesT + ((long)63 * 2048 + m0) * 512;
#pragma unroll
      for (int i = 0; i < 8; ++i) {
        int idx = i * 512 + tid, row = idx >> 6, u = idx & 63;
        *(u32x4*)(sX0b + sxo(row, u * 16)) =
            __builtin_nontemporal_load((const u32x4*)(src + (long)row * 512 + u * 8));
      }
    } else {
      u32x4 av[8];
#pragma unroll
      for (int i = 0; i < 8; ++i) {
        int idx = i * 512 + tid, row = idx >> 6, u = idx & 63;
        av[i] = ld16_sys(aB + (long)row * 1024 + u * 16);
      }
      asm volatile("s_waitcnt vmcnt(0)" ::: "memory");
      __builtin_amdgcn_sched_barrier(0);
#pragma unroll
      for (int i = 0; i < 8; ++i) {
        int idx = i * 512 + tid, row = idx >> 6, u = idx & 63;
        *(u32x4*)(sX0b + sxo(row, u * 16)) = av[i];
      }
    }
    if (!symPhase) {
      const u16* src = boxesT + ((long)(62 - t) * 2048 + m0) * 512;
#pragma unroll
      for (int i = 0; i < 8; ++i) {
        int idx = i * 512 + tid, row = idx >> 6, u = idx & 63;
        *(u32x4*)(sX1b + sxo(row, u * 16)) =
            __builtin_nontemporal_load((const u32x4*)(src + (long)row * 512 + u * 8));
      }
    }
    __syncthreads();  // stage complete; vmcnt drained -> clean counted pipeline

    const u16* WA = symPhase ? Sl : Wl;
    const int nch = symPhase ? 16 : 32;
    const long gWoff = ((long)(c * 128 + gn)) * 512 + (gkb >> 1);

    f32x4 C[4];
#pragma unroll
    for (int j = 0; j < 4; ++j) C[j] = (f32x4){0.f, 0.f, 0.f, 0.f};

    // prologue: chunks 0,1 -> bufs 0,1
    if (symPhase) {
      load_lds16(WA + gWoff,      sW + 0 * 4096 + tid * 8);
      load_lds16(WA + gWoff + 32, sW + 1 * 4096 + tid * 8);
    } else {
      load_lds16(WA + gWoff, sW + 0 * 4096 + tid * 8);
      load_lds16(Wr + gWoff, sW + 1 * 4096 + tid * 8);
    }
    for (int ci = 0; ci < nch; ++ci) {
      if (ci + 1 < nch) asm volatile("s_waitcnt vmcnt(1)" ::: "memory");
      else              asm volatile("s_waitcnt vmcnt(0)" ::: "memory");
      __builtin_amdgcn_s_barrier();
      asm volatile("" ::: "memory");
      if (ci + 2 < nch) {
        int cj = ci + 2;
        int u = symPhase ? cj : (cj >> 1);
        const u16* s = (symPhase || !(cj & 1)) ? (WA + gWoff + u * 32) : (Wr + gWoff + u * 32);
        load_lds16(s, sW + (cj % 3) * 4096 + tid * 8);
      }
      {
        const char* bufb = (const char*)sW + (ci % 3) * 8192;
        int u = symPhase ? ci : (ci >> 1);
        const char* ab = (!symPhase && (ci & 1)) ? sX1b : sX0b;
        int akb = (u * 64 + qq * 16) ^ aX;
        bf16x8 af = *(const bf16x8*)(ab + arow * 1024 + akb);
#pragma unroll
        for (int j = 0; j < 4; ++j)
          C[j] = __builtin_amdgcn_mfma_f32_16x16x32_bf16(
              af, *(const bf16x8*)(bufb + hb[j]), C[j], 0, 0, 0);
      }
    }
    __syncthreads();  // laggards done reading sX0/sW before overlay writes

    // hoisted P-weight prologue: in flight under epilogue + fence
    const u16* WP = symPhase ? Ss : Ws;
    const long gPoff = ((long)(c * 64 + pr)) * 1024 + (pkb >> 1);
    load_lds16(WP + gPoff + 0 * 64, sW + 0 * 4096 + tid * 8);
    load_lds16(WP + gPoff + 1 * 64, sW + 1 * 4096 + tid * 8);

    // ---- H epilogue: tanh(+bias [+sym@Sr]) -> pack -> coherent store to hG ----
    if (symPhase) {
      float* sSymF = (float*)(sX0b + 20480);
      int symp = 78 - t;
      sSymF[tid] = sym[((long)(m0 + (tid >> 3)) * 16 + symp) * 8 + (tid & 7)];
      __syncthreads();
    }
    u16* sP = (u16*)sX0b;
#pragma unroll
    for (int j = 0; j < 4; ++j) {
      int lcol = wc2 * 64 + j * 16 + l16;
      int col = c * 128 + lcol;
      if (!symPhase) {
        float bn = bl[col];
#pragma unroll
        for (int rr = 0; rr < 4; ++rr) {
          int m = wr2 * 16 + qq * 4 + rr;
          sP[m * 136 + lcol] = f2bf(fast_tanh(C[j][rr] + bn));
        }
      } else {
        float bn = sbl[col] + sbr[col];
        float sr[8];
        *(float4*)&sr[0] = *(const float4*)&SrF[(long)col * 8];
        *(float4*)&sr[4] = *(const float4*)&SrF[(long)col * 8 + 4];
        const float* sSymF = (const float*)(sX0b + 20480);
#pragma unroll
        for (int rr = 0; rr < 4; ++rr) {
          int m = wr2 * 16 + qq * 4 + rr;
          float v = C[j][rr] + bn;
          const float* sv = sSymF + m * 8;
#pragma unroll
          for (int k = 0; k < 8; ++k) v += sv[k] * sr[k];
          sP[m * 136 + lcol] = f2bf(fast_tanh(v));
        }
      }
    }
    __syncthreads();
#pragma unroll
    for (int i = 0; i < 2; ++i) {
      int g = i * 512 + tid, row = g >> 4, cu = g & 15;
      u32x4 v = *(const u32x4*)(sX0b + row * 272 + cu * 16);
      st16_sys(hB + (long)row * 2048 + c * 256 + cu * 16, v);
    }
    // ---- group fence (8 blocks sharing r): h written ----
    __syncthreads();  // drains store vmcnt
    if (tid == 0) {
      u32* f = fence + (2 * t) * 32 + r;
      __hip_atomic_fetch_add(f, 1u, __ATOMIC_RELAXED, __HIP_MEMORY_SCOPE_AGENT);
      while (__hip_atomic_load(f, __ATOMIC_RELAXED, __HIP_MEMORY_SCOPE_AGENT) < 8u)
        __builtin_amdgcn_s_sleep(2);
    }
    __syncthreads();
    asm volatile("" ::: "memory");

    // ================= P phase: stage h (coherent, batched) =================
#pragma unroll
    for (int half = 0; half < 2; ++half) {
      u32x4 hv[8];
#pragma unroll
      for (int i = 0; i < 8; ++i) {
        int g = (half * 8 + i) * 512 + tid, row = g >> 7, u = g & 127;
        hv[i] = ld16_sys(hB + (long)row * 2048 + u * 16);
      }
      asm volatile("s_waitcnt vmcnt(0)" ::: "memory");
      __builtin_amdgcn_sched_barrier(0);
#pragma unroll
      for (int i = 0; i < 8; ++i) {
        int g = (half * 8 + i) * 512 + tid, row = g >> 7, u = g & 127;
        if (u < 64) *(u32x4*)(sX0b + sxo(row, u * 16)) = hv[i];
        else        *(u32x4*)(sX1b + sxo(row, (u - 64) * 16)) = hv[i];
      }
    }
    __syncthreads();
    if (last) {  // out writes will alias hG: wait until ALL blocks staged h
      if (tid == 0) {
        u32* f = fence + 5056;
        __hip_atomic_fetch_add(f, 1u, __ATOMIC_RELAXED, __HIP_MEMORY_SCOPE_AGENT);
        while (__hip_atomic_load(f, __ATOMIC_RELAXED, __HIP_MEMORY_SCOPE_AGENT) < 256u)
          __builtin_amdgcn_s_sleep(2);
      }
      __syncthreads();
      asm volatile("" ::: "memory");
    }

    f32x4 D[2];
    D[0] = (f32x4){0.f, 0.f, 0.f, 0.f};
    D[1] = (f32x4){0.f, 0.f, 0.f, 0.f};
    for (int ci = 0; ci < 16; ++ci) {
      if (ci + 1 < 16) asm volatile("s_waitcnt vmcnt(1)" ::: "memory");
      else             asm volatile("s_waitcnt vmcnt(0)" ::: "memory");
      __builtin_amdgcn_s_barrier();
      asm volatile("" ::: "memory");
      if (ci + 2 < 16) {
        int cj = ci + 2;
        load_lds16(WP + gPoff + cj * 64, sW + (cj % 3) * 4096 + tid * 8);
      }
      {
        const char* bufb = (const char*)sW + (ci % 3) * 8192;
        const char* ab = (ci < 8) ? sX0b : sX1b;
        int base = (ci & 7) * 128;
#pragma unroll
        for (int s1 = 0; s1 < 2; ++s1) {
          int akb = (base + s1 * 64 + qq * 16) ^ aX;
          bf16x8 af = *(const bf16x8*)(ab + arow * 1024 + akb);
#pragma unroll
          for (int j = 0; j < 2; ++j)
            D[j] = __builtin_amdgcn_mfma_f32_16x16x32_bf16(
                af, *(const bf16x8*)(bufb + pb[j][s1]), D[j], 0, 0, 0);
        }
      }
    }
    __syncthreads();  // laggards done reading sX0/sX1/sW

    // ---- P epilogue ----
    const float* b2 = symPhase ? sbs : bs;
    if (!last) {
#pragma unroll
      for (int j = 0; j < 2; ++j) {
        int lcol = wc2 * 32 + j * 16 + l16;
        float bn = b2[c * 64 + lcol];
#pragma unroll
        for (int rr = 0; rr < 4; ++rr) {
          int m = wr2 * 16 + qq * 4 + rr;
          sP[m * 72 + lcol] = f2bf(fast_tanh(D[j][rr] + bn));
        }
      }
      __syncthreads();
      {
        int row = tid >> 3, cu = tid & 7;
        u32x4 v = *(const u32x4*)(sX0b + row * 144 + cu * 16);
        st16_sys(aB + (long)row * 1024 + c * 128 + cu * 16, v);
      }
      // ---- group fence: acc written ----
      __syncthreads();
      if (tid == 0) {
        u32* f = fence + (2 * t + 1) * 32 + r;
        __hip_atomic_fetch_add(f, 1u, __ATOMIC_RELAXED, __HIP_MEMORY_SCOPE_AGENT);
        while (__hip_atomic_load(f, __ATOMIC_RELAXED, __HIP_MEMORY_SCOPE_AGENT) < 8u)
          __builtin_amdgcn_s_sleep(2);
      }
      __syncthreads();
      asm volatile("" ::: "memory");
    } else {
#pragma unroll
      for (int j = 0; j < 2; ++j) {
        int lcol = wc2 * 32 + j * 16 + l16;
        int col = c * 64 + lcol;
        float bn = b2[col];
#pragma unroll
        for (int rr = 0; rr < 4; ++rr) {
          int m = wr2 * 16 + qq * 4 + rr;
          outF[(long)(m0 + m) * 512 + col] = fast_tanh(D[j][rr] + bn);
        }
      }
    }
  }
}

// ================= fallback kernels (small-ws path) =================
__global__ __launch_bounds__(256) void box_all_v2(const float* __restrict__ inp,
    const float* __restrict__ Wb, const float* __restrict__ bb, u16* __restrict__ boxes) {
  int b = blockIdx.x, t = threadIdx.x;
  __shared__ float sin_[64][12];
  for (int idx = t; idx < 768; idx += 256) sin_[idx / 12][idx % 12] = inp[(long)b * 768 + idx];
  const int f0 = t * 2;
  float w0[12], w1[12];
#pragma unroll
  for (int q = 0; q < 12; ++q) { w0[q] = Wb[f0 * 12 + q]; w1[q] = Wb[(f0 + 1) * 12 + q]; }
  float b0 = bb[f0], b1 = bb[f0 + 1];
  __syncthreads();
  for (int i = 0; i < 64; ++i) {
    float a0 = b0, a1 = b1;
#pragma unroll
    for (int q = 0; q < 12; ++q) { float x = sin_[i][q]; a0 += x * w0[q]; a1 += x * w1[q]; }
    u32 pk = (u32)f2bf(fast_tanh(a0)) | ((u32)f2bf(fast_tanh(a1)) << 16);
    *(u32*)&boxes[(((long)b * 64 + i) * 512) + f0] = pk;
  }
}

__global__ __launch_bounds__(256) void gemm64(
    const u16* __restrict__ A1, int lda1,
    const u16* __restrict__ W1b, const float* __restrict__ W1f, int K1,
    const u16* __restrict__ A2, int lda2,
    const u16* __restrict__ W2b, const float* __restrict__ W2f, int K2,
    const float* __restrict__ bias,
    const float* __restrict__ symS, const float* __restrict__ Srw, const float* __restrict__ sbr,
    int doTanh, int outMode,
    u16* __restrict__ Cb, float* __restrict__ Cf, int N) {
  __shared__ u16 As[64][72];
  __shared__ u16 Bs[64][72];
  const int tid = threadIdx.x;
  const int lane = tid & 63, w = tid >> 6;
  const int wr = w >> 1, wc = w & 1;
  const int quad = lane >> 4, l16 = lane & 15;
  const int m0 = blockIdx.y * 64, n0 = blockIdx.x * 64;
  const int srow = tid >> 2, scol = (tid & 3) * 16;
  f32x4 acc[2][2];
#pragma unroll
  for (int i = 0; i < 2; ++i)
#pragma unroll
    for (int j = 0; j < 2; ++j) acc[i][j] = (f32x4){0.f, 0.f, 0.f, 0.f};
#pragma unroll
  for (int pair = 0; pair < 2; ++pair) {
    const u16* A = pair ? A2 : A1;
    const u16* Wb_ = pair ? W2b : W1b;
    const float* Wf_ = pair ? W2f : W1f;
    const int lda = pair ? lda2 : lda1;
    const int K = pair ? K2 : K1;
    if (K == 0) continue;
    for (int k0 = 0; k0 < K; k0 += 64) {
      const u16* ap = &A[(long)(m0 + srow) * lda + k0 + scol];
      uint4 av0 = *(const uint4*)ap;
      uint4 av1 = *(const uint4*)(ap + 8);
      uint4 bv0, bv1;
      if (Wb_) {
        const u16* wp = &Wb_[(long)(n0 + srow) * K + k0 + scol];
        bv0 = *(const uint4*)wp;
        bv1 = *(const uint4*)(wp + 8);
      } else {
        const float* wp = &Wf_[(long)(n0 + srow) * K + k0 + scol];
        u16 tv[16];
#pragma unroll
        for (int qq = 0; qq < 16; ++qq) tv[qq] = f2bf(wp[qq]);
        bv0 = ((uint4*)tv)[0];
        bv1 = ((uint4*)tv)[1];
      }
      __syncthreads();
      *(uint4*)&As[srow][scol] = av0;
      *(uint4*)&As[srow][scol + 8] = av1;
      *(uint4*)&Bs[srow][scol] = bv0;
      *(uint4*)&Bs[srow][scol + 8] = bv1;
      __syncthreads();
      bf16x8 af[2][2], bfv[2][2];
#pragma unroll
      for (int kk = 0; kk < 2; ++kk) {
#pragma unroll
        for (int i = 0; i < 2; ++i)
          af[i][kk] = *(const bf16x8*)&As[wr * 32 + i * 16 + l16][kk * 32 + quad * 8];
#pragma unroll
        for (int j = 0; j < 2; ++j)
          bfv[j][kk] = *(const bf16x8*)&Bs[wc * 32 + j * 16 + l16][kk * 32 + quad * 8];
      }
#pragma unroll
      for (int kk = 0; kk < 2; ++kk)
#pragma unroll
        for (int i = 0; i < 2; ++i)
#pragma unroll
          for (int j = 0; j < 2; ++j)
            acc[i][j] = __builtin_amdgcn_mfma_f32_16x16x32_bf16(af[i][kk], bfv[j][kk], acc[i][j], 0, 0, 0);
    }
  }
#pragma unroll
  for (int j = 0; j < 2; ++j) {
    const int n = n0 + wc * 32 + j * 16 + l16;
    float bn = bias ? bias[n] : 0.0f;
    float srn[8];
    if (symS) {
      bn += sbr[n];
#pragma unroll
      for (int qq = 0; qq < 8; ++qq) srn[qq] = Srw[n * 8 + qq];
    }
#pragma unroll
    for (int i = 0; i < 2; ++i) {
#pragma unroll
      for (int r = 0; r < 4; ++r) {
        const int m = m0 + wr * 32 + i * 16 + quad * 4 + r;
        float v = acc[i][j][r] + bn;
        if (symS) {
#pragma unroll
          for (int qq = 0; qq < 8; ++qq) v += symS[(long)m * 128 + qq] * srn[qq];
        }
        if (doTanh) v = fast_tanh(v);
        if (outMode == 0) Cb[(long)m * N + n] = f2bf(v);
        else Cf[(long)m * N + n] = v;
      }
    }
  }
}

extern "C" void kernel_launch(void* const* d_in, const int* in_sizes, int n_in,
                              void* d_out, int out_size, void* d_ws, size_t ws_size,
                              hipStream_t stream) {
  const float* inp = (const float*)d_in[0];
  const float* sym = (const float*)d_in[1];
  const float* Wb  = (const float*)d_in[3];
  const float* bb  = (const float*)d_in[4];
  const float* Wl  = (const float*)d_in[5];
  const float* bl  = (const float*)d_in[6];
  const float* Wr  = (const float*)d_in[7];
  const float* Ws  = (const float*)d_in[8];
  const float* bs  = (const float*)d_in[9];
  const float* Sl  = (const float*)d_in[10];
  const float* sbl = (const float*)d_in[11];
  const float* Sr  = (const float*)d_in[12];
  const float* sbr = (const float*)d_in[13];
  const float* Ss  = (const float*)d_in[14];
  const float* sbs = (const float*)d_in[15];

  const long B = 2048, NB = 64, F = 512, H = 1024;
  const long WE = 524288;
  u16* ws = (u16*)d_ws;
  dim3 blk(256);

  // fused path: 5 bf16 weights + boxesT + fence (~139.5 MB)
  const size_t baseU16 = (size_t)5 * WE + (size_t)64 * B * F;
  const size_t needNew = baseU16 * 2 + 20480;

  if (ws_size >= needNew) {
    u16* WlB = ws;
    u16* WrB = WlB + WE;
    u16* WsB = WrB + WE;
    u16* SlB = WsB + WE;
    u16* SsB = SlB + WE;
    u16* boxesT = SsB + WE;                        // [64][2048][512]
    u16* accG = boxesT + (size_t)63 * 2048 * 512;  // overlay: boxesT[63] dead after t=0
    u16* hG = (u16*)d_out;                         // 4 MB scratch until final out
    u32* fence = (u32*)(ws + baseU16);             // 79*2*32 group slots + global slot

    (void)hipMemsetAsync(fence, 0, 20480, stream);
    cvt_bf16<<<WE / 2048, blk, 0, stream>>>(Wl, WlB, (int)WE);
    cvt_bf16<<<WE / 2048, blk, 0, stream>>>(Wr, WrB, (int)WE);
    cvt_bf16<<<WE / 2048, blk, 0, stream>>>(Ws, WsB, (int)WE);
    cvt_bf16<<<WE / 2048, blk, 0, stream>>>(Sl, SlB, (int)WE);
    cvt_bf16<<<WE / 2048, blk, 0, stream>>>(Ss, SsB, (int)WE);
    box_allT<<<B, blk, 0, stream>>>(inp, Wb, bb, boxesT);
    chain2<<<dim3(256), dim3(512), 0, stream>>>(boxesT, WlB, WrB, WsB, SlB, SsB,
                                                bl, bs, sbl, sbr, sbs, Sr, sym,
                                                accG, hG, (float*)d_out, fence);
  } else {
    // fallback: bf16 weights if they fit, else fp32 staging
    dim3 gH(16, 32), gP(8, 32);
    const size_t szW = 5 * WE * 2, szBoxes = (size_t)B * NB * F * 2;
    const size_t szH = (size_t)B * H * 2, szAcc = (size_t)B * F * 2;
    const size_t needT2 = szW + szBoxes + szH + szAcc;
    const size_t needT3 = szBoxes + szH + szAcc;
    int tier = (ws_size >= needT2) ? 2 : (ws_size >= needT3) ? 3 : 4;
    u16 *WlB = nullptr, *WrB = nullptr, *WsB = nullptr, *SlB = nullptr, *SsB = nullptr;
    const float *WlF = Wl, *WrF = Wr, *WsF = Ws, *SlF = Sl, *SsF = Ss;
    u16* p = ws;
    if (tier == 2) {
      WlB = p; WrB = p + WE; WsB = p + 2 * WE; SlB = p + 3 * WE; SsB = p + 4 * WE;
      p += 5 * WE;
      cvt_bf16<<<WE / 2048, blk, 0, stream>>>(Wl, WlB, (int)WE);
      cvt_bf16<<<WE / 2048, blk, 0, stream>>>(Wr, WrB, (int)WE);
      cvt_bf16<<<WE / 2048, blk, 0, stream>>>(Ws, WsB, (int)WE);
      cvt_bf16<<<WE / 2048, blk, 0, stream>>>(Sl, SlB, (int)WE);
      cvt_bf16<<<WE / 2048, blk, 0, stream>>>(Ss, SsB, (int)WE);
      WlF = WrF = WsF = SlF = SsF = nullptr;
    }
    u16* boxes = p;
    p += B * NB * F;
    u16* hBuf = p; p += B * H;
    u16* accBuf = p;
    box_all_v2<<<B, blk, 0, stream>>>(inp, Wb, bb, boxes);
    const u16* curA = boxes + 63 * 512;
    int curLda = (int)(NB * F);
    for (int bp = 62; bp >= 0; --bp) {
      gemm64<<<gH, blk, 0, stream>>>(curA, curLda, WlB, WlF, 512,
                                     boxes + (long)bp * 512, (int)(NB * F), WrB, WrF, 512,
                                     bl, nullptr, nullptr, nullptr, 1, 0, hBuf, nullptr, 1024);
      gemm64<<<gP, blk, 0, stream>>>(hBuf, 1024, WsB, WsF, 1024,
                                     nullptr, 0, nullptr, nullptr, 0,
                                     bs, nullptr, nullptr, nullptr, 1, 0, accBuf, nullptr, 512);
      curA = accBuf; curLda = 512;
    }
    for (int symp = 15; symp >= 0; --symp) {
      gemm64<<<gH, blk, 0, stream>>>(accBuf, 512, SlB, SlF, 512,
                                     nullptr, 0, nullptr, nullptr, 0,
                                     sbl, sym + symp * 8, Sr, sbr, 1, 0, hBuf, nullptr, 1024);
      int om = (symp == 0) ? 1 : 0;
      gemm64<<<gP, blk, 0, stream>>>(hBuf, 1024, SsB, SsF, 1024,
                                     nullptr, 0, nullptr, nullptr, 0,
                                     sbs, nullptr, nullptr, nullptr, 1, om, accBuf, (float*)d_out, 512);
    }
  }
  (void)in_sizes; (void)n_in; (void)out_size;
}